// Round 14
// baseline (159.343 us; speedup 1.0000x reference)
//
#include <hip/hip_runtime.h>
#include <hip/hip_bf16.h>
#include <math.h>

#define N_NODES 100000
#define N_EDGES 1600000
#define BUCKET_SHIFT 8
#define NBUCKETS ((N_NODES + 255) >> 8)      // 391 buckets of 256 nodes
#define BCAP 6144                            // mean 4096, sigma ~64 -> 32 sigma margin
#define NPROJ_BLOCKS ((N_NODES + 63) / 64)   // 1563 (64 nodes/block, 16/wave)
#define SCAT_BLOCKS ((N_EDGES / 4 + 2047) / 2048)  // 196 (8192 edges/block)
#define BINS_PER 128                         // csr: bins per sub-block (2 per bucket)

typedef unsigned short ushort_t;
typedef __attribute__((ext_vector_type(8))) short bf16x8;   // 8 bf16 in 4 VGPRs
typedef __attribute__((ext_vector_type(4))) float f32x4;

union U8 { uint4 u; bf16x8 b; };

// pack two fp32 -> one uint of 2 bf16 (RTN-even) via compiler-lowered cvt_pk
__device__ inline unsigned pkbf16(float lo, float hi) {
    __hip_bfloat162 h = __float22bfloat162_rn(make_float2(lo, hi));
    return *reinterpret_cast<unsigned*>(&h);
}
__device__ inline float blo(unsigned w) { return __uint_as_float(w << 16); }
__device__ inline float bhi(unsigned w) { return __uint_as_float(w & 0xFFFF0000u); }

// ---------------------------------------------------------------------------
// K0: one-time prep. Transpose Wq/Wk/Wv/Wo (fp32 row-major [k][col]) into
// bf16 Wt[mat][col][k] (contiguous k -> MFMA A-fragments are single uint4
// loads). Also zeroes bucket cursors + the elist global counter.
// ---------------------------------------------------------------------------
__global__ __launch_bounds__(256) void wtrans_kernel(
    const float* __restrict__ Wq, const float* __restrict__ Wk,
    const float* __restrict__ Wv, const float* __restrict__ Wo,
    ushort_t* __restrict__ Wt, int* __restrict__ cursor)
{
    int t = threadIdx.x;
    for (int i = t; i < 512; i += 256) cursor[i] = 0;   // cursors + gctr
    int c = t & 63;
    int k0 = (t >> 6) * 16;
    const float* srcs[4] = {Wq, Wk, Wv, Wo};
    #pragma unroll
    for (int m = 0; m < 4; ++m) {
        const float* Wsrc = srcs[m];
        ushort_t* dst = Wt + m * 4096;
        unsigned p[8];
        #pragma unroll
        for (int j = 0; j < 8; ++j) {
            float lo = Wsrc[(k0 + 2 * j) * 64 + c];
            float hi = Wsrc[(k0 + 2 * j + 1) * 64 + c];
            p[j] = pkbf16(lo, hi);
        }
        *(uint4*)&dst[c * 64 + k0]     = make_uint4(p[0], p[1], p[2], p[3]);
        *(uint4*)&dst[c * 64 + k0 + 8] = make_uint4(p[4], p[5], p[6], p[7]);
    }
}

// ---------------------------------------------------------------------------
// K1: Q/KV projection via MFMA 16x16x32 bf16 (swapped operands; see R13).
// ---------------------------------------------------------------------------
__global__ __launch_bounds__(256) void qkv_kernel(
    const float* __restrict__ x, const ushort_t* __restrict__ Wt,
    const float* __restrict__ bq, const float* __restrict__ bk,
    const float* __restrict__ bv,
    float* __restrict__ Q, ushort_t* __restrict__ KVb)
{
    int tid = threadIdx.x;
    int lane = tid & 63;
    int w = tid >> 6;
    int node = blockIdx.x * 64 + w * 16 + (lane & 15);
    int nclamp = node < N_NODES ? node : N_NODES - 1;
    int koff = (lane >> 4) * 8;

    U8 xf[2];
    #pragma unroll
    for (int kh = 0; kh < 2; ++kh) {
        const float* xb = &x[(size_t)nclamp * 64 + kh * 32 + koff];
        float4 a0 = *(const float4*)xb;
        float4 a1 = *(const float4*)(xb + 4);
        unsigned* xp = (unsigned*)&xf[kh];
        xp[0] = pkbf16(a0.x, a0.y); xp[1] = pkbf16(a0.z, a0.w);
        xp[2] = pkbf16(a1.x, a1.y); xp[3] = pkbf16(a1.z, a1.w);
    }

    f32x4 acc[3][4];
    #pragma unroll
    for (int m = 0; m < 3; ++m)
        #pragma unroll
        for (int ct = 0; ct < 4; ++ct)
            acc[m][ct] = (f32x4){0.f, 0.f, 0.f, 0.f};

    int colin = lane & 15;
    #pragma unroll
    for (int m = 0; m < 3; ++m) {
        const ushort_t* Wm = Wt + m * 4096;
        #pragma unroll
        for (int ct = 0; ct < 4; ++ct) {
            const ushort_t* wb = &Wm[(ct * 16 + colin) * 64 + koff];
            #pragma unroll
            for (int kh = 0; kh < 2; ++kh) {
                U8 wf;
                wf.u = *(const uint4*)(wb + kh * 32);
                acc[m][ct] = __builtin_amdgcn_mfma_f32_16x16x32_bf16(
                    wf.b, xf[kh].b, acc[m][ct], 0, 0, 0);
            }
        }
    }

    if (node < N_NODES) {
        int wc4 = (lane >> 4) * 4;
        #pragma unroll
        for (int ct = 0; ct < 4; ++ct) {
            int wc = ct * 16 + wc4;
            float4 qb = *(const float4*)&bq[wc];
            f32x4 a = acc[0][ct];
            *(float4*)&Q[(size_t)node * 64 + wc] =
                make_float4(a[0] + qb.x, a[1] + qb.y, a[2] + qb.z, a[3] + qb.w);
            float4 kb = *(const float4*)&bk[wc];
            f32x4 k = acc[1][ct];
            *(uint2*)&KVb[(size_t)node * 128 + wc] =
                make_uint2(pkbf16(k[0] + kb.x, k[1] + kb.y), pkbf16(k[2] + kb.z, k[3] + kb.w));
            float4 vb = *(const float4*)&bv[wc];
            f32x4 v = acc[2][ct];
            *(uint2*)&KVb[(size_t)node * 128 + 64 + wc] =
                make_uint2(pkbf16(v[0] + vb.x, v[1] + vb.y), pkbf16(v[2] + vb.z, v[3] + vb.w));
        }
    }
}

// ---------------------------------------------------------------------------
// Pass 1: bucket scatter, 1024 threads x 8192 edges per block (196 blocks).
// ---------------------------------------------------------------------------
__global__ __launch_bounds__(1024) void scatter_kernel(
    const int* __restrict__ ei, int* __restrict__ cursor,
    unsigned int* __restrict__ pairs)
{
    __shared__ int hist[NBUCKETS];
    __shared__ int bbs[NBUCKETS];
    int t = threadIdx.x;
    for (int i = t; i < NBUCKETS; i += 1024) hist[i] = 0;
    __syncthreads();

    const int4* r4 = (const int4*)ei;
    const int4* c4 = (const int4*)(ei + N_EDGES);
    int ia = blockIdx.x * 2048 + t;
    int ib = ia + 1024;
    bool va = (ia < N_EDGES / 4), vb = (ib < N_EDGES / 4);
    int4 rva = va ? r4[ia] : make_int4(0, 0, 0, 0);
    int4 cva = va ? c4[ia] : make_int4(0, 0, 0, 0);
    int4 rvb = vb ? r4[ib] : make_int4(0, 0, 0, 0);
    int4 cvb = vb ? c4[ib] : make_int4(0, 0, 0, 0);

    int rr[8], cc[8];
    rr[0] = rva.x; rr[1] = rva.y; rr[2] = rva.z; rr[3] = rva.w;
    rr[4] = rvb.x; rr[5] = rvb.y; rr[6] = rvb.z; rr[7] = rvb.w;
    cc[0] = cva.x; cc[1] = cva.y; cc[2] = cva.z; cc[3] = cva.w;
    cc[4] = cvb.x; cc[5] = cvb.y; cc[6] = cvb.z; cc[7] = cvb.w;

    int bkt[8], rnk[8];
    unsigned pk[8];
    #pragma unroll
    for (int j = 0; j < 8; ++j) {
        bool v = (j < 4) ? va : vb;
        int b = rr[j] >> BUCKET_SHIFT;
        bkt[j] = b;
        rnk[j] = v ? atomicAdd(&hist[b], 1) : 0;
        pk[j] = ((unsigned)(rr[j] & 255) << 17) | (unsigned)cc[j];
    }
    __syncthreads();
    for (int i = t; i < NBUCKETS; i += 1024) {
        int h = hist[i];
        if (h) bbs[i] = i * BCAP + atomicAdd(&cursor[i], h);
    }
    __syncthreads();
    #pragma unroll
    for (int j = 0; j < 8; ++j) {
        bool v = (j < 4) ? va : vb;
        if (v) pairs[bbs[bkt[j]] + rnk[j]] = pk[j];
    }
}

// ---------------------------------------------------------------------------
// Pass 2: CSR build, TWO blocks per bucket (782 light blocks, ~1 KB LDS, all
// resident -> no serial second round; R13's 391 heavy blocks took 1.53
// rounds). Sub-block `half` owns node-bins [half*128, half*128+128). Each
// sub-block compacts its nodes' edges into its own elist range reserved by
// ONE atomicAdd(gctr) — segment order across nodes is irrelevant, agg only
// needs per-node (start, deg). pairs read twice from L2 (no LDS staging,
// no in-place hazard).
// ---------------------------------------------------------------------------
__global__ __launch_bounds__(256) void csr_build_kernel(
    const unsigned int* __restrict__ pairs, const int* __restrict__ cursor,
    int* __restrict__ deg, int* __restrict__ start,
    int* __restrict__ elist, int* __restrict__ gctr)
{
    __shared__ int hist[BINS_PER], scn[BINS_PER];
    __shared__ int basep;
    int blk = blockIdx.x;
    int b = blk >> 1;
    int half = blk & 1;
    int t = threadIdx.x;
    int cnt = cursor[b];
    const unsigned int* bp = pairs + (size_t)b * BCAP;

    if (t < BINS_PER) hist[t] = 0;
    __syncthreads();
    for (int i = t; i < cnt; i += 256) {
        int bin = bp[i] >> 17;
        if ((bin >> 7) == half) atomicAdd(&hist[bin & 127], 1);
    }
    __syncthreads();

    int h = 0;
    if (t < BINS_PER) { h = hist[t]; scn[t] = h; }
    __syncthreads();
    for (int off = 1; off < BINS_PER; off <<= 1) {
        int u = (t >= off && t < BINS_PER) ? scn[t - off] : 0;
        __syncthreads();
        if (t < BINS_PER) scn[t] += u;
        __syncthreads();
    }
    if (t == BINS_PER - 1) basep = atomicAdd(gctr, scn[t]);  // reserve range
    __syncthreads();
    int base = basep;
    if (t < BINS_PER) {
        int excl = scn[t] - h;
        int node = (b << BUCKET_SHIFT) + half * BINS_PER + t;
        if (node < N_NODES) { deg[node] = h; start[node] = base + excl; }
        hist[t] = excl;                      // reuse as local cursor
    }
    __syncthreads();
    for (int i = t; i < cnt; i += 256) {
        unsigned p = bp[i];
        int bin = p >> 17;
        if ((bin >> 7) == half) {
            int pos = base + atomicAdd(&hist[bin & 127], 1);
            elist[pos] = (int)(p & 0x1FFFFu);
        }
    }
}

// ---------------------------------------------------------------------------
// K6: per-node softmax aggregation (see R12/R13). Epilogue now writes the
// agg row as BF16 (uint4 per lane) to aggb — out_kernel loads MFMA fragments
// from it directly (no fp32 round trip).
// ---------------------------------------------------------------------------
#define AGG_LOAD(JB, KW, VW, PJ)                                              \
    int j##PJ = (JB) + e;                                                     \
    {                                                                         \
        int jc = (j##PJ < d) ? j##PJ : (d - 1);                               \
        int c = elist[st + jc];                                               \
        const ushort_t* row = KVb + (size_t)c * 128;                          \
        KW = *(const uint4*)(row + h * 8);                                    \
        VW = *(const uint4*)(row + 64 + h * 8);                               \
    }

#define AGG_COMPUTE(KW, VW, PJ)                                               \
    {                                                                         \
        float dot = blo(KW.x) * q0.x + bhi(KW.x) * q0.y                       \
                  + blo(KW.y) * q0.z + bhi(KW.y) * q0.w                       \
                  + blo(KW.z) * q1.x + bhi(KW.z) * q1.y                       \
                  + blo(KW.w) * q1.z + bhi(KW.w) * q1.w;                      \
        float pe = (j##PJ < d) ? __expf(dot * inv_scale) : 0.f;               \
        s += pe;                                                              \
        acc[0] = fmaf(pe, blo(VW.x), acc[0]);                                 \
        acc[1] = fmaf(pe, bhi(VW.x), acc[1]);                                 \
        acc[2] = fmaf(pe, blo(VW.y), acc[2]);                                 \
        acc[3] = fmaf(pe, bhi(VW.y), acc[3]);                                 \
        acc[4] = fmaf(pe, blo(VW.z), acc[4]);                                 \
        acc[5] = fmaf(pe, bhi(VW.z), acc[5]);                                 \
        acc[6] = fmaf(pe, blo(VW.w), acc[6]);                                 \
        acc[7] = fmaf(pe, bhi(VW.w), acc[7]);                                 \
    }

__global__ __launch_bounds__(256) void agg_kernel(
    const float* __restrict__ Q, const ushort_t* __restrict__ KVb,
    const int* __restrict__ start, const int* __restrict__ deg,
    const int* __restrict__ elist, ushort_t* __restrict__ aggb)
{
    int tid = threadIdx.x;
    int lane = tid & 63;
    int e = lane >> 3;
    int h = lane & 7;
    int n = blockIdx.x * 4 + (tid >> 6);     // grid 25000 -> n < 100000 exact

    int d = deg[n];
    int st = start[n];

    float4 q0 = *(const float4*)&Q[n * 64 + h * 8];
    float4 q1 = *(const float4*)&Q[n * 64 + h * 8 + 4];

    const float inv_scale = 0.35355339059327373f;  // 1/sqrt(8)
    float s = 0.f;
    float acc[8] = {0.f, 0.f, 0.f, 0.f, 0.f, 0.f, 0.f, 0.f};

    for (int j0 = 0; j0 < d; j0 += 16) {
        uint4 kwA, vwA;
        AGG_LOAD(j0, kwA, vwA, A)
        if (j0 + 8 < d) {
            uint4 kwB, vwB;
            AGG_LOAD(j0 + 8, kwB, vwB, B)
            AGG_COMPUTE(kwA, vwA, A)
            AGG_COMPUTE(kwB, vwB, B)
        } else {
            AGG_COMPUTE(kwA, vwA, A)
        }
    }

    #pragma unroll
    for (int off = 8; off <= 32; off <<= 1) {
        s += __shfl_xor(s, off);
        #pragma unroll
        for (int i = 0; i < 8; ++i) acc[i] += __shfl_xor(acc[i], off);
    }
    if (lane < 8) {                           // e==0 lanes: head h = lane
        float inv = 1.f / (s + 1e-8f);
        *(uint4*)&aggb[(size_t)n * 64 + lane * 8] = make_uint4(
            pkbf16(acc[0] * inv, acc[1] * inv), pkbf16(acc[2] * inv, acc[3] * inv),
            pkbf16(acc[4] * inv, acc[5] * inv), pkbf16(acc[6] * inv, acc[7] * inv));
    }
}

// ---------------------------------------------------------------------------
// K7: output projection via MFMA. B-fragments load DIRECTLY from bf16 aggb
// (uint4 = ready-made bf16x8). Writes d_out fp32.
// ---------------------------------------------------------------------------
__global__ __launch_bounds__(256) void out_kernel(
    const ushort_t* __restrict__ aggb, const ushort_t* __restrict__ Wto,
    const float* __restrict__ bo, float* __restrict__ out)
{
    int tid = threadIdx.x;
    int lane = tid & 63;
    int w = tid >> 6;
    int node = blockIdx.x * 64 + w * 16 + (lane & 15);
    int nclamp = node < N_NODES ? node : N_NODES - 1;
    int koff = (lane >> 4) * 8;

    U8 af[2];
    #pragma unroll
    for (int kh = 0; kh < 2; ++kh)
        af[kh].u = *(const uint4*)&aggb[(size_t)nclamp * 64 + kh * 32 + koff];

    f32x4 acc[4];
    #pragma unroll
    for (int ct = 0; ct < 4; ++ct) acc[ct] = (f32x4){0.f, 0.f, 0.f, 0.f};

    int colin = lane & 15;
    #pragma unroll
    for (int ct = 0; ct < 4; ++ct) {
        const ushort_t* wb = &Wto[(ct * 16 + colin) * 64 + koff];
        #pragma unroll
        for (int kh = 0; kh < 2; ++kh) {
            U8 wf;
            wf.u = *(const uint4*)(wb + kh * 32);
            acc[ct] = __builtin_amdgcn_mfma_f32_16x16x32_bf16(
                wf.b, af[kh].b, acc[ct], 0, 0, 0);
        }
    }

    if (node < N_NODES) {
        int wc4 = (lane >> 4) * 4;
        #pragma unroll
        for (int ct = 0; ct < 4; ++ct) {
            int wc = ct * 16 + wc4;
            float4 ob = *(const float4*)&bo[wc];
            f32x4 a = acc[ct];
            *(float4*)&out[(size_t)node * 64 + wc] =
                make_float4(a[0] + ob.x, a[1] + ob.y, a[2] + ob.z, a[3] + ob.w);
        }
    }
}

extern "C" void kernel_launch(void* const* d_in, const int* in_sizes, int n_in,
                              void* d_out, int out_size, void* d_ws, size_t ws_size,
                              hipStream_t stream)
{
    const float* x  = (const float*)d_in[0];
    const int*   ei = (const int*)  d_in[1];   // [2*E] flattened: row then col
    const float* Wq = (const float*)d_in[2];
    const float* bq = (const float*)d_in[3];
    const float* Wk = (const float*)d_in[4];
    const float* bk = (const float*)d_in[5];
    const float* Wv = (const float*)d_in[6];
    const float* bv = (const float*)d_in[7];
    const float* Wo = (const float*)d_in[8];
    const float* bo = (const float*)d_in[9];
    float* out = (float*)d_out;

    float* Q = (float*)d_ws;                               // N*64 f32           25.6 MB
    ushort_t* KVb = (ushort_t*)(Q + (size_t)N_NODES * 64); // N*128 bf16         25.6 MB
    ushort_t* aggb = KVb + (size_t)N_NODES * 128;          // N*64 bf16          12.8 MB
    int* deg    = (int*)(aggb + (size_t)N_NODES * 64);     //                     0.4 MB
    int* start  = deg + N_NODES;                           //                     0.4 MB
    int* cursor = start + N_NODES;                         // 512 ints (counts + gctr)
    int* gctr   = cursor + 400;
    unsigned int* pairs = (unsigned int*)(cursor + 512);   // NBUCKETS*BCAP       9.6 MB
    int* elist  = (int*)(pairs + (size_t)NBUCKETS * BCAP); // N_EDGES             6.4 MB
    ushort_t* Wt = (ushort_t*)(elist + N_EDGES);           // 4*64*64 bf16        32 KB

    wtrans_kernel<<<1, 256, 0, stream>>>(Wq, Wk, Wv, Wo, Wt, cursor);
    qkv_kernel<<<NPROJ_BLOCKS, 256, 0, stream>>>(x, Wt, bq, bk, bv, Q, KVb);
    scatter_kernel<<<SCAT_BLOCKS, 1024, 0, stream>>>(ei, cursor, pairs);
    csr_build_kernel<<<2 * NBUCKETS, 256, 0, stream>>>(pairs, cursor, deg, start, elist, gctr);
    agg_kernel<<<25000, 256, 0, stream>>>(Q, KVb, start, deg, elist, aggb);
    out_kernel<<<NPROJ_BLOCKS, 256, 0, stream>>>(aggb, Wt + 3 * 4096, bo, out);
}

// Round 15
// 149.786 us; speedup vs baseline: 1.0638x; 1.0638x over previous
//
#include <hip/hip_runtime.h>
#include <hip/hip_bf16.h>
#include <math.h>

#define N_NODES 100000
#define N_EDGES 1600000
#define BUCKET_SHIFT 8
#define NBUCKETS ((N_NODES + 255) >> 8)      // 391 buckets of 256 nodes
#define BCAP 6144                            // mean 4096, sigma ~64 -> 32 sigma margin
#define NPROJ_BLOCKS ((N_NODES + 63) / 64)   // 1563 (64 nodes/block, 16/wave)
#define SCAT_BLOCKS ((N_EDGES / 4 + 2047) / 2048)  // 196 (8192 edges/block)

typedef unsigned short ushort_t;
typedef __attribute__((ext_vector_type(8))) short bf16x8;   // 8 bf16 in 4 VGPRs
typedef __attribute__((ext_vector_type(4))) float f32x4;

union U8 { uint4 u; bf16x8 b; };

// pack two fp32 -> one uint of 2 bf16 (RTN-even) via compiler-lowered cvt_pk
__device__ inline unsigned pkbf16(float lo, float hi) {
    __hip_bfloat162 h = __float22bfloat162_rn(make_float2(lo, hi));
    return *reinterpret_cast<unsigned*>(&h);
}
__device__ inline float blo(unsigned w) { return __uint_as_float(w << 16); }
__device__ inline float bhi(unsigned w) { return __uint_as_float(w & 0xFFFF0000u); }

// ---------------------------------------------------------------------------
// K0: one-time prep. Transpose Wq/Wk/Wv/Wo (fp32 row-major [k][col]) into
// bf16 Wt[mat][col][k] (contiguous k -> MFMA A-fragments are single uint4
// loads). Also zeroes bucket cursors.
// ---------------------------------------------------------------------------
__global__ __launch_bounds__(256) void wtrans_kernel(
    const float* __restrict__ Wq, const float* __restrict__ Wk,
    const float* __restrict__ Wv, const float* __restrict__ Wo,
    ushort_t* __restrict__ Wt, int* __restrict__ cursor)
{
    int t = threadIdx.x;
    for (int i = t; i < 512; i += 256) cursor[i] = 0;
    int c = t & 63;
    int k0 = (t >> 6) * 16;
    const float* srcs[4] = {Wq, Wk, Wv, Wo};
    #pragma unroll
    for (int m = 0; m < 4; ++m) {
        const float* Wsrc = srcs[m];
        ushort_t* dst = Wt + m * 4096;
        unsigned p[8];
        #pragma unroll
        for (int j = 0; j < 8; ++j) {
            float lo = Wsrc[(k0 + 2 * j) * 64 + c];
            float hi = Wsrc[(k0 + 2 * j + 1) * 64 + c];
            p[j] = pkbf16(lo, hi);
        }
        *(uint4*)&dst[c * 64 + k0]     = make_uint4(p[0], p[1], p[2], p[3]);
        *(uint4*)&dst[c * 64 + k0 + 8] = make_uint4(p[4], p[5], p[6], p[7]);
    }
}

// ---------------------------------------------------------------------------
// K1: Q/KV projection via MFMA 16x16x32 bf16 (swapped operands; see R13).
// ---------------------------------------------------------------------------
__global__ __launch_bounds__(256) void qkv_kernel(
    const float* __restrict__ x, const ushort_t* __restrict__ Wt,
    const float* __restrict__ bq, const float* __restrict__ bk,
    const float* __restrict__ bv,
    float* __restrict__ Q, ushort_t* __restrict__ KVb)
{
    int tid = threadIdx.x;
    int lane = tid & 63;
    int w = tid >> 6;
    int node = blockIdx.x * 64 + w * 16 + (lane & 15);
    int nclamp = node < N_NODES ? node : N_NODES - 1;
    int koff = (lane >> 4) * 8;

    U8 xf[2];
    #pragma unroll
    for (int kh = 0; kh < 2; ++kh) {
        const float* xb = &x[(size_t)nclamp * 64 + kh * 32 + koff];
        float4 a0 = *(const float4*)xb;
        float4 a1 = *(const float4*)(xb + 4);
        unsigned* xp = (unsigned*)&xf[kh];
        xp[0] = pkbf16(a0.x, a0.y); xp[1] = pkbf16(a0.z, a0.w);
        xp[2] = pkbf16(a1.x, a1.y); xp[3] = pkbf16(a1.z, a1.w);
    }

    f32x4 acc[3][4];
    #pragma unroll
    for (int m = 0; m < 3; ++m)
        #pragma unroll
        for (int ct = 0; ct < 4; ++ct)
            acc[m][ct] = (f32x4){0.f, 0.f, 0.f, 0.f};

    int colin = lane & 15;
    #pragma unroll
    for (int m = 0; m < 3; ++m) {
        const ushort_t* Wm = Wt + m * 4096;
        #pragma unroll
        for (int ct = 0; ct < 4; ++ct) {
            const ushort_t* wb = &Wm[(ct * 16 + colin) * 64 + koff];
            #pragma unroll
            for (int kh = 0; kh < 2; ++kh) {
                U8 wf;
                wf.u = *(const uint4*)(wb + kh * 32);
                acc[m][ct] = __builtin_amdgcn_mfma_f32_16x16x32_bf16(
                    wf.b, xf[kh].b, acc[m][ct], 0, 0, 0);
            }
        }
    }

    if (node < N_NODES) {
        int wc4 = (lane >> 4) * 4;
        #pragma unroll
        for (int ct = 0; ct < 4; ++ct) {
            int wc = ct * 16 + wc4;
            float4 qb = *(const float4*)&bq[wc];
            f32x4 a = acc[0][ct];
            *(float4*)&Q[(size_t)node * 64 + wc] =
                make_float4(a[0] + qb.x, a[1] + qb.y, a[2] + qb.z, a[3] + qb.w);
            float4 kb = *(const float4*)&bk[wc];
            f32x4 k = acc[1][ct];
            *(uint2*)&KVb[(size_t)node * 128 + wc] =
                make_uint2(pkbf16(k[0] + kb.x, k[1] + kb.y), pkbf16(k[2] + kb.z, k[3] + kb.w));
            float4 vb = *(const float4*)&bv[wc];
            f32x4 v = acc[2][ct];
            *(uint2*)&KVb[(size_t)node * 128 + 64 + wc] =
                make_uint2(pkbf16(v[0] + vb.x, v[1] + vb.y), pkbf16(v[2] + vb.z, v[3] + vb.w));
        }
    }
}

// ---------------------------------------------------------------------------
// Pass 1: bucket scatter, 1024 threads x 8192 edges per block (196 blocks).
// ---------------------------------------------------------------------------
__global__ __launch_bounds__(1024) void scatter_kernel(
    const int* __restrict__ ei, int* __restrict__ cursor,
    unsigned int* __restrict__ pairs)
{
    __shared__ int hist[NBUCKETS];
    __shared__ int bbs[NBUCKETS];
    int t = threadIdx.x;
    for (int i = t; i < NBUCKETS; i += 1024) hist[i] = 0;
    __syncthreads();

    const int4* r4 = (const int4*)ei;
    const int4* c4 = (const int4*)(ei + N_EDGES);
    int ia = blockIdx.x * 2048 + t;
    int ib = ia + 1024;
    bool va = (ia < N_EDGES / 4), vb = (ib < N_EDGES / 4);
    int4 rva = va ? r4[ia] : make_int4(0, 0, 0, 0);
    int4 cva = va ? c4[ia] : make_int4(0, 0, 0, 0);
    int4 rvb = vb ? r4[ib] : make_int4(0, 0, 0, 0);
    int4 cvb = vb ? c4[ib] : make_int4(0, 0, 0, 0);

    int rr[8], cc[8];
    rr[0] = rva.x; rr[1] = rva.y; rr[2] = rva.z; rr[3] = rva.w;
    rr[4] = rvb.x; rr[5] = rvb.y; rr[6] = rvb.z; rr[7] = rvb.w;
    cc[0] = cva.x; cc[1] = cva.y; cc[2] = cva.z; cc[3] = cva.w;
    cc[4] = cvb.x; cc[5] = cvb.y; cc[6] = cvb.z; cc[7] = cvb.w;

    int bkt[8], rnk[8];
    unsigned pk[8];
    #pragma unroll
    for (int j = 0; j < 8; ++j) {
        bool v = (j < 4) ? va : vb;
        int b = rr[j] >> BUCKET_SHIFT;
        bkt[j] = b;
        rnk[j] = v ? atomicAdd(&hist[b], 1) : 0;
        pk[j] = ((unsigned)(rr[j] & 255) << 17) | (unsigned)cc[j];
    }
    __syncthreads();
    for (int i = t; i < NBUCKETS; i += 1024) {
        int h = hist[i];
        if (h) bbs[i] = i * BCAP + atomicAdd(&cursor[i], h);
    }
    __syncthreads();
    #pragma unroll
    for (int j = 0; j < 8; ++j) {
        bool v = (j < 4) ? va : vb;
        if (v) pairs[bbs[bkt[j]] + rnk[j]] = pk[j];
    }
}

// ---------------------------------------------------------------------------
// Pass 2 (R13 version, reverted): one block per bucket. Stage pairs in LDS,
// 256-bin histogram + scan -> deg/start; write ordered col ids back IN PLACE
// (elist aliases pairs, padded at b*BCAP). start[n] = b*BCAP + excl.
// ---------------------------------------------------------------------------
__global__ __launch_bounds__(256) void csr_build_kernel(
    unsigned int* __restrict__ pairs, const int* __restrict__ cursor,
    int* __restrict__ deg, int* __restrict__ start)
{
    __shared__ unsigned int lp[BCAP];        // 24 KB
    __shared__ int hist[256], scn[256];
    int b = blockIdx.x, t = threadIdx.x;
    int cnt = cursor[b];
    unsigned int* bp = pairs + (size_t)b * BCAP;

    for (int i = t; i < cnt; i += 256) lp[i] = bp[i];
    hist[t] = 0;
    __syncthreads();
    for (int i = t; i < cnt; i += 256) atomicAdd(&hist[lp[i] >> 17], 1);
    __syncthreads();

    int h = hist[t];
    scn[t] = h;
    __syncthreads();
    for (int off = 1; off < 256; off <<= 1) {
        int u = (t >= off) ? scn[t - off] : 0;
        __syncthreads();
        scn[t] += u;
        __syncthreads();
    }
    int excl = scn[t] - h;
    int node = (b << BUCKET_SHIFT) + t;
    if (node < N_NODES) { deg[node] = h; start[node] = b * BCAP + excl; }
    hist[t] = excl;                          // reuse as local cursor
    __syncthreads();
    for (int i = t; i < cnt; i += 256) {
        unsigned p = lp[i];
        int pos = atomicAdd(&hist[p >> 17], 1);
        bp[pos] = p & 0x1FFFFu;              // ordered col id, in place
    }
}

// ---------------------------------------------------------------------------
// K6: per-node softmax aggregation, lane = (node-slot ln = lane>>3, head h =
// lane&7) — 8 nodes per wave. head_dim=8 => each lane's 8-dim dot is fully
// in-register AND softmax (s) is per-(node,head) => s and acc are LANE-LOCAL:
// zero cross-lane ops anywhere (R12-R14's 27-shfl epilogue gone). Per-lane
// degree loop (exec-mask divergence, wave runs max d of its 8 nodes; masked
// lanes issue no VMEM). Unroll-2 keeps 2 edges in flight. Q reads and aggb
// writes are fully contiguous per wave (2 KB / 1 KB).
// ---------------------------------------------------------------------------
__global__ __launch_bounds__(256) void agg_kernel(
    const float* __restrict__ Q, const ushort_t* __restrict__ KVb,
    const int* __restrict__ start, const int* __restrict__ deg,
    const int* __restrict__ elist, ushort_t* __restrict__ aggb)
{
    int tid = threadIdx.x;
    int lane = tid & 63;
    int h = lane & 7;
    int w = blockIdx.x * 4 + (tid >> 6);     // grid 3125 -> w < 12500
    int n = w * 8 + (lane >> 3);             // 12500*8 = 100000 exact

    int d = deg[n];
    int st = start[n];

    float4 q0 = *(const float4*)&Q[(size_t)n * 64 + h * 8];
    float4 q1 = *(const float4*)&Q[(size_t)n * 64 + h * 8 + 4];

    const float inv_scale = 0.35355339059327373f;  // 1/sqrt(8)
    float s = 0.f;
    float acc[8] = {0.f, 0.f, 0.f, 0.f, 0.f, 0.f, 0.f, 0.f};

    int j = 0;
    for (; j + 2 <= d; j += 2) {
        int c0 = elist[st + j];
        int c1 = elist[st + j + 1];
        const ushort_t* r0 = KVb + (size_t)c0 * 128;
        const ushort_t* r1 = KVb + (size_t)c1 * 128;
        uint4 kw0 = *(const uint4*)(r0 + h * 8);
        uint4 vw0 = *(const uint4*)(r0 + 64 + h * 8);
        uint4 kw1 = *(const uint4*)(r1 + h * 8);
        uint4 vw1 = *(const uint4*)(r1 + 64 + h * 8);

        float d0 = blo(kw0.x) * q0.x + bhi(kw0.x) * q0.y
                 + blo(kw0.y) * q0.z + bhi(kw0.y) * q0.w
                 + blo(kw0.z) * q1.x + bhi(kw0.z) * q1.y
                 + blo(kw0.w) * q1.z + bhi(kw0.w) * q1.w;
        float d1 = blo(kw1.x) * q0.x + bhi(kw1.x) * q0.y
                 + blo(kw1.y) * q0.z + bhi(kw1.y) * q0.w
                 + blo(kw1.z) * q1.x + bhi(kw1.z) * q1.y
                 + blo(kw1.w) * q1.z + bhi(kw1.w) * q1.w;
        float p0 = __expf(d0 * inv_scale);
        float p1 = __expf(d1 * inv_scale);
        s += p0 + p1;
        acc[0] = fmaf(p0, blo(vw0.x), fmaf(p1, blo(vw1.x), acc[0]));
        acc[1] = fmaf(p0, bhi(vw0.x), fmaf(p1, bhi(vw1.x), acc[1]));
        acc[2] = fmaf(p0, blo(vw0.y), fmaf(p1, blo(vw1.y), acc[2]));
        acc[3] = fmaf(p0, bhi(vw0.y), fmaf(p1, bhi(vw1.y), acc[3]));
        acc[4] = fmaf(p0, blo(vw0.z), fmaf(p1, blo(vw1.z), acc[4]));
        acc[5] = fmaf(p0, bhi(vw0.z), fmaf(p1, bhi(vw1.z), acc[5]));
        acc[6] = fmaf(p0, blo(vw0.w), fmaf(p1, blo(vw1.w), acc[6]));
        acc[7] = fmaf(p0, bhi(vw0.w), fmaf(p1, bhi(vw1.w), acc[7]));
    }
    if (j < d) {
        int c0 = elist[st + j];
        const ushort_t* r0 = KVb + (size_t)c0 * 128;
        uint4 kw0 = *(const uint4*)(r0 + h * 8);
        uint4 vw0 = *(const uint4*)(r0 + 64 + h * 8);
        float d0 = blo(kw0.x) * q0.x + bhi(kw0.x) * q0.y
                 + blo(kw0.y) * q0.z + bhi(kw0.y) * q0.w
                 + blo(kw0.z) * q1.x + bhi(kw0.z) * q1.y
                 + blo(kw0.w) * q1.z + bhi(kw0.w) * q1.w;
        float p0 = __expf(d0 * inv_scale);
        s += p0;
        acc[0] = fmaf(p0, blo(vw0.x), acc[0]);
        acc[1] = fmaf(p0, bhi(vw0.x), acc[1]);
        acc[2] = fmaf(p0, blo(vw0.y), acc[2]);
        acc[3] = fmaf(p0, bhi(vw0.y), acc[3]);
        acc[4] = fmaf(p0, blo(vw0.z), acc[4]);
        acc[5] = fmaf(p0, bhi(vw0.z), acc[5]);
        acc[6] = fmaf(p0, blo(vw0.w), acc[6]);
        acc[7] = fmaf(p0, bhi(vw0.w), acc[7]);
    }

    float inv = 1.f / (s + 1e-8f);
    *(uint4*)&aggb[(size_t)n * 64 + h * 8] = make_uint4(
        pkbf16(acc[0] * inv, acc[1] * inv), pkbf16(acc[2] * inv, acc[3] * inv),
        pkbf16(acc[4] * inv, acc[5] * inv), pkbf16(acc[6] * inv, acc[7] * inv));
}

// ---------------------------------------------------------------------------
// K7: output projection via MFMA. B-fragments load DIRECTLY from bf16 aggb
// (uint4 = ready-made bf16x8). Writes d_out fp32.
// ---------------------------------------------------------------------------
__global__ __launch_bounds__(256) void out_kernel(
    const ushort_t* __restrict__ aggb, const ushort_t* __restrict__ Wto,
    const float* __restrict__ bo, float* __restrict__ out)
{
    int tid = threadIdx.x;
    int lane = tid & 63;
    int w = tid >> 6;
    int node = blockIdx.x * 64 + w * 16 + (lane & 15);
    int nclamp = node < N_NODES ? node : N_NODES - 1;
    int koff = (lane >> 4) * 8;

    U8 af[2];
    #pragma unroll
    for (int kh = 0; kh < 2; ++kh)
        af[kh].u = *(const uint4*)&aggb[(size_t)nclamp * 64 + kh * 32 + koff];

    f32x4 acc[4];
    #pragma unroll
    for (int ct = 0; ct < 4; ++ct) acc[ct] = (f32x4){0.f, 0.f, 0.f, 0.f};

    int colin = lane & 15;
    #pragma unroll
    for (int ct = 0; ct < 4; ++ct) {
        const ushort_t* wb = &Wto[(ct * 16 + colin) * 64 + koff];
        #pragma unroll
        for (int kh = 0; kh < 2; ++kh) {
            U8 wf;
            wf.u = *(const uint4*)(wb + kh * 32);
            acc[ct] = __builtin_amdgcn_mfma_f32_16x16x32_bf16(
                wf.b, af[kh].b, acc[ct], 0, 0, 0);
        }
    }

    if (node < N_NODES) {
        int wc4 = (lane >> 4) * 4;
        #pragma unroll
        for (int ct = 0; ct < 4; ++ct) {
            int wc = ct * 16 + wc4;
            float4 ob = *(const float4*)&bo[wc];
            f32x4 a = acc[ct];
            *(float4*)&out[(size_t)node * 64 + wc] =
                make_float4(a[0] + ob.x, a[1] + ob.y, a[2] + ob.z, a[3] + ob.w);
        }
    }
}

extern "C" void kernel_launch(void* const* d_in, const int* in_sizes, int n_in,
                              void* d_out, int out_size, void* d_ws, size_t ws_size,
                              hipStream_t stream)
{
    const float* x  = (const float*)d_in[0];
    const int*   ei = (const int*)  d_in[1];   // [2*E] flattened: row then col
    const float* Wq = (const float*)d_in[2];
    const float* bq = (const float*)d_in[3];
    const float* Wk = (const float*)d_in[4];
    const float* bk = (const float*)d_in[5];
    const float* Wv = (const float*)d_in[6];
    const float* bv = (const float*)d_in[7];
    const float* Wo = (const float*)d_in[8];
    const float* bo = (const float*)d_in[9];
    float* out = (float*)d_out;

    float* Q = (float*)d_ws;                               // N*64 f32           25.6 MB
    ushort_t* KVb = (ushort_t*)(Q + (size_t)N_NODES * 64); // N*128 bf16         25.6 MB
    ushort_t* aggb = KVb + (size_t)N_NODES * 128;          // N*64 bf16          12.8 MB
    int* deg    = (int*)(aggb + (size_t)N_NODES * 64);
    int* start  = deg + N_NODES;
    int* cursor = start + N_NODES;                         // 512 ints
    unsigned int* pairs = (unsigned int*)(cursor + 512);   // NBUCKETS*BCAP (elist aliases)
    ushort_t* Wt = (ushort_t*)(pairs + (size_t)NBUCKETS * BCAP);  // 4*64*64 bf16

    wtrans_kernel<<<1, 256, 0, stream>>>(Wq, Wk, Wv, Wo, Wt, cursor);
    qkv_kernel<<<NPROJ_BLOCKS, 256, 0, stream>>>(x, Wt, bq, bk, bv, Q, KVb);
    scatter_kernel<<<SCAT_BLOCKS, 1024, 0, stream>>>(ei, cursor, pairs);
    csr_build_kernel<<<NBUCKETS, 256, 0, stream>>>(pairs, cursor, deg, start);
    agg_kernel<<<3125, 256, 0, stream>>>(Q, KVb, start, deg, (const int*)pairs, aggb);
    out_kernel<<<NPROJ_BLOCKS, 256, 0, stream>>>(aggb, Wt + 3 * 4096, bo, out);
}

// Round 16
// 148.109 us; speedup vs baseline: 1.0758x; 1.0113x over previous
//
#include <hip/hip_runtime.h>
#include <hip/hip_bf16.h>
#include <math.h>

#define N_NODES 100000
#define N_EDGES 1600000
#define BUCKET_SHIFT 8
#define NBUCKETS ((N_NODES + 255) >> 8)      // 391 buckets of 256 nodes
#define BCAP 6144                            // mean 4096, sigma ~64 -> 32 sigma margin
#define NPROJ_BLOCKS ((N_NODES + 63) / 64)   // 1563 (64 nodes/block, 16/wave)
#define SCAT_BLOCKS ((N_EDGES / 4 + 2047) / 2048)  // 196 (8192 edges/block)

typedef unsigned short ushort_t;
typedef __attribute__((ext_vector_type(8))) short bf16x8;   // 8 bf16 in 4 VGPRs
typedef __attribute__((ext_vector_type(4))) float f32x4;

union U8 { uint4 u; bf16x8 b; };

// pack two fp32 -> one uint of 2 bf16 (RTN-even) via compiler-lowered cvt_pk
__device__ inline unsigned pkbf16(float lo, float hi) {
    __hip_bfloat162 h = __float22bfloat162_rn(make_float2(lo, hi));
    return *reinterpret_cast<unsigned*>(&h);
}
__device__ inline float blo(unsigned w) { return __uint_as_float(w << 16); }
__device__ inline float bhi(unsigned w) { return __uint_as_float(w & 0xFFFF0000u); }

// ---------------------------------------------------------------------------
// K0: one-time prep. Transpose Wq/Wk/Wv/Wo (fp32 row-major [k][col]) into
// bf16 Wt[mat][col][k]. Also zeroes bucket cursors.
// ---------------------------------------------------------------------------
__global__ __launch_bounds__(256) void wtrans_kernel(
    const float* __restrict__ Wq, const float* __restrict__ Wk,
    const float* __restrict__ Wv, const float* __restrict__ Wo,
    ushort_t* __restrict__ Wt, int* __restrict__ cursor)
{
    int t = threadIdx.x;
    for (int i = t; i < 512; i += 256) cursor[i] = 0;
    int c = t & 63;
    int k0 = (t >> 6) * 16;
    const float* srcs[4] = {Wq, Wk, Wv, Wo};
    #pragma unroll
    for (int m = 0; m < 4; ++m) {
        const float* Wsrc = srcs[m];
        ushort_t* dst = Wt + m * 4096;
        unsigned p[8];
        #pragma unroll
        for (int j = 0; j < 8; ++j) {
            float lo = Wsrc[(k0 + 2 * j) * 64 + c];
            float hi = Wsrc[(k0 + 2 * j + 1) * 64 + c];
            p[j] = pkbf16(lo, hi);
        }
        *(uint4*)&dst[c * 64 + k0]     = make_uint4(p[0], p[1], p[2], p[3]);
        *(uint4*)&dst[c * 64 + k0 + 8] = make_uint4(p[4], p[5], p[6], p[7]);
    }
}

// ---------------------------------------------------------------------------
// K1: Q/KV projection via MFMA 16x16x32 bf16 (swapped operands; see R13).
// ---------------------------------------------------------------------------
__global__ __launch_bounds__(256) void qkv_kernel(
    const float* __restrict__ x, const ushort_t* __restrict__ Wt,
    const float* __restrict__ bq, const float* __restrict__ bk,
    const float* __restrict__ bv,
    float* __restrict__ Q, ushort_t* __restrict__ KVb)
{
    int tid = threadIdx.x;
    int lane = tid & 63;
    int w = tid >> 6;
    int node = blockIdx.x * 64 + w * 16 + (lane & 15);
    int nclamp = node < N_NODES ? node : N_NODES - 1;
    int koff = (lane >> 4) * 8;

    U8 xf[2];
    #pragma unroll
    for (int kh = 0; kh < 2; ++kh) {
        const float* xb = &x[(size_t)nclamp * 64 + kh * 32 + koff];
        float4 a0 = *(const float4*)xb;
        float4 a1 = *(const float4*)(xb + 4);
        unsigned* xp = (unsigned*)&xf[kh];
        xp[0] = pkbf16(a0.x, a0.y); xp[1] = pkbf16(a0.z, a0.w);
        xp[2] = pkbf16(a1.x, a1.y); xp[3] = pkbf16(a1.z, a1.w);
    }

    f32x4 acc[3][4];
    #pragma unroll
    for (int m = 0; m < 3; ++m)
        #pragma unroll
        for (int ct = 0; ct < 4; ++ct)
            acc[m][ct] = (f32x4){0.f, 0.f, 0.f, 0.f};

    int colin = lane & 15;
    #pragma unroll
    for (int m = 0; m < 3; ++m) {
        const ushort_t* Wm = Wt + m * 4096;
        #pragma unroll
        for (int ct = 0; ct < 4; ++ct) {
            const ushort_t* wb = &Wm[(ct * 16 + colin) * 64 + koff];
            #pragma unroll
            for (int kh = 0; kh < 2; ++kh) {
                U8 wf;
                wf.u = *(const uint4*)(wb + kh * 32);
                acc[m][ct] = __builtin_amdgcn_mfma_f32_16x16x32_bf16(
                    wf.b, xf[kh].b, acc[m][ct], 0, 0, 0);
            }
        }
    }

    if (node < N_NODES) {
        int wc4 = (lane >> 4) * 4;
        #pragma unroll
        for (int ct = 0; ct < 4; ++ct) {
            int wc = ct * 16 + wc4;
            float4 qb = *(const float4*)&bq[wc];
            f32x4 a = acc[0][ct];
            *(float4*)&Q[(size_t)node * 64 + wc] =
                make_float4(a[0] + qb.x, a[1] + qb.y, a[2] + qb.z, a[3] + qb.w);
            float4 kb = *(const float4*)&bk[wc];
            f32x4 k = acc[1][ct];
            *(uint2*)&KVb[(size_t)node * 128 + wc] =
                make_uint2(pkbf16(k[0] + kb.x, k[1] + kb.y), pkbf16(k[2] + kb.z, k[3] + kb.w));
            float4 vb = *(const float4*)&bv[wc];
            f32x4 v = acc[2][ct];
            *(uint2*)&KVb[(size_t)node * 128 + 64 + wc] =
                make_uint2(pkbf16(v[0] + vb.x, v[1] + vb.y), pkbf16(v[2] + vb.z, v[3] + vb.w));
        }
    }
}

// ---------------------------------------------------------------------------
// Pass 1: bucket scatter, 1024 threads x 8192 edges per block (196 blocks).
// ---------------------------------------------------------------------------
__global__ __launch_bounds__(1024) void scatter_kernel(
    const int* __restrict__ ei, int* __restrict__ cursor,
    unsigned int* __restrict__ pairs)
{
    __shared__ int hist[NBUCKETS];
    __shared__ int bbs[NBUCKETS];
    int t = threadIdx.x;
    for (int i = t; i < NBUCKETS; i += 1024) hist[i] = 0;
    __syncthreads();

    const int4* r4 = (const int4*)ei;
    const int4* c4 = (const int4*)(ei + N_EDGES);
    int ia = blockIdx.x * 2048 + t;
    int ib = ia + 1024;
    bool va = (ia < N_EDGES / 4), vb = (ib < N_EDGES / 4);
    int4 rva = va ? r4[ia] : make_int4(0, 0, 0, 0);
    int4 cva = va ? c4[ia] : make_int4(0, 0, 0, 0);
    int4 rvb = vb ? r4[ib] : make_int4(0, 0, 0, 0);
    int4 cvb = vb ? c4[ib] : make_int4(0, 0, 0, 0);

    int rr[8], cc[8];
    rr[0] = rva.x; rr[1] = rva.y; rr[2] = rva.z; rr[3] = rva.w;
    rr[4] = rvb.x; rr[5] = rvb.y; rr[6] = rvb.z; rr[7] = rvb.w;
    cc[0] = cva.x; cc[1] = cva.y; cc[2] = cva.z; cc[3] = cva.w;
    cc[4] = cvb.x; cc[5] = cvb.y; cc[6] = cvb.z; cc[7] = cvb.w;

    int bkt[8], rnk[8];
    unsigned pk[8];
    #pragma unroll
    for (int j = 0; j < 8; ++j) {
        bool v = (j < 4) ? va : vb;
        int b = rr[j] >> BUCKET_SHIFT;
        bkt[j] = b;
        rnk[j] = v ? atomicAdd(&hist[b], 1) : 0;
        pk[j] = ((unsigned)(rr[j] & 255) << 17) | (unsigned)cc[j];
    }
    __syncthreads();
    for (int i = t; i < NBUCKETS; i += 1024) {
        int h = hist[i];
        if (h) bbs[i] = i * BCAP + atomicAdd(&cursor[i], h);
    }
    __syncthreads();
    #pragma unroll
    for (int j = 0; j < 8; ++j) {
        bool v = (j < 4) ? va : vb;
        if (v) pairs[bbs[bkt[j]] + rnk[j]] = pk[j];
    }
}

// ---------------------------------------------------------------------------
// Pass 2: one block per bucket. Stage pairs in LDS, 256-bin histogram + scan
// -> deg/start; write ordered col ids back IN PLACE (elist aliases pairs,
// padded at b*BCAP). start[n] = b*BCAP + excl.
// ---------------------------------------------------------------------------
__global__ __launch_bounds__(256) void csr_build_kernel(
    unsigned int* __restrict__ pairs, const int* __restrict__ cursor,
    int* __restrict__ deg, int* __restrict__ start)
{
    __shared__ unsigned int lp[BCAP];        // 24 KB
    __shared__ int hist[256], scn[256];
    int b = blockIdx.x, t = threadIdx.x;
    int cnt = cursor[b];
    unsigned int* bp = pairs + (size_t)b * BCAP;

    for (int i = t; i < cnt; i += 256) lp[i] = bp[i];
    hist[t] = 0;
    __syncthreads();
    for (int i = t; i < cnt; i += 256) atomicAdd(&hist[lp[i] >> 17], 1);
    __syncthreads();

    int h = hist[t];
    scn[t] = h;
    __syncthreads();
    for (int off = 1; off < 256; off <<= 1) {
        int u = (t >= off) ? scn[t - off] : 0;
        __syncthreads();
        scn[t] += u;
        __syncthreads();
    }
    int excl = scn[t] - h;
    int node = (b << BUCKET_SHIFT) + t;
    if (node < N_NODES) { deg[node] = h; start[node] = b * BCAP + excl; }
    hist[t] = excl;                          // reuse as local cursor
    __syncthreads();
    for (int i = t; i < cnt; i += 256) {
        unsigned p = lp[i];
        int pos = atomicAdd(&hist[p >> 17], 1);
        bp[pos] = p & 0x1FFFFu;              // ordered col id, in place
    }
}

// ---------------------------------------------------------------------------
// K6: per-node softmax aggregation, lane = (node-slot, head) — s and acc
// lane-local, zero cross-lane ops (R15). NEW: 4 edges in flight per lane —
// all 4 elist loads issued, then all 8 KV-slice loads, then compute (agg is
// latency-bound: R15 showed VALUBusy 30%, 3.1 TB/s with only 2 outstanding).
// ---------------------------------------------------------------------------
#define DOT8(KW) (blo(KW.x) * q0.x + bhi(KW.x) * q0.y                         \
                + blo(KW.y) * q0.z + bhi(KW.y) * q0.w                         \
                + blo(KW.z) * q1.x + bhi(KW.z) * q1.y                         \
                + blo(KW.w) * q1.z + bhi(KW.w) * q1.w)

#define ACC8(P, VW)                                                           \
    acc[0] = fmaf(P, blo(VW.x), acc[0]);                                      \
    acc[1] = fmaf(P, bhi(VW.x), acc[1]);                                      \
    acc[2] = fmaf(P, blo(VW.y), acc[2]);                                      \
    acc[3] = fmaf(P, bhi(VW.y), acc[3]);                                      \
    acc[4] = fmaf(P, blo(VW.z), acc[4]);                                      \
    acc[5] = fmaf(P, bhi(VW.z), acc[5]);                                      \
    acc[6] = fmaf(P, blo(VW.w), acc[6]);                                      \
    acc[7] = fmaf(P, bhi(VW.w), acc[7]);

__global__ __launch_bounds__(256) void agg_kernel(
    const float* __restrict__ Q, const ushort_t* __restrict__ KVb,
    const int* __restrict__ start, const int* __restrict__ deg,
    const int* __restrict__ elist, ushort_t* __restrict__ aggb)
{
    int tid = threadIdx.x;
    int lane = tid & 63;
    int h = lane & 7;
    int w = blockIdx.x * 4 + (tid >> 6);     // grid 3125 -> w < 12500
    int n = w * 8 + (lane >> 3);             // 12500*8 = 100000 exact

    int d = deg[n];
    int st = start[n];

    float4 q0 = *(const float4*)&Q[(size_t)n * 64 + h * 8];
    float4 q1 = *(const float4*)&Q[(size_t)n * 64 + h * 8 + 4];

    const float inv_scale = 0.35355339059327373f;  // 1/sqrt(8)
    float s = 0.f;
    float acc[8] = {0.f, 0.f, 0.f, 0.f, 0.f, 0.f, 0.f, 0.f};

    int j = 0;
    for (; j + 4 <= d; j += 4) {
        int c0 = elist[st + j];
        int c1 = elist[st + j + 1];
        int c2 = elist[st + j + 2];
        int c3 = elist[st + j + 3];
        const ushort_t* r0 = KVb + (size_t)c0 * 128;
        const ushort_t* r1 = KVb + (size_t)c1 * 128;
        const ushort_t* r2 = KVb + (size_t)c2 * 128;
        const ushort_t* r3 = KVb + (size_t)c3 * 128;
        uint4 kw0 = *(const uint4*)(r0 + h * 8);
        uint4 kw1 = *(const uint4*)(r1 + h * 8);
        uint4 kw2 = *(const uint4*)(r2 + h * 8);
        uint4 kw3 = *(const uint4*)(r3 + h * 8);
        uint4 vw0 = *(const uint4*)(r0 + 64 + h * 8);
        uint4 vw1 = *(const uint4*)(r1 + 64 + h * 8);
        uint4 vw2 = *(const uint4*)(r2 + 64 + h * 8);
        uint4 vw3 = *(const uint4*)(r3 + 64 + h * 8);

        float p0 = __expf(DOT8(kw0) * inv_scale);
        float p1 = __expf(DOT8(kw1) * inv_scale);
        float p2 = __expf(DOT8(kw2) * inv_scale);
        float p3 = __expf(DOT8(kw3) * inv_scale);
        s += (p0 + p1) + (p2 + p3);
        ACC8(p0, vw0)
        ACC8(p1, vw1)
        ACC8(p2, vw2)
        ACC8(p3, vw3)
    }
    for (; j < d; ++j) {
        int c0 = elist[st + j];
        const ushort_t* r0 = KVb + (size_t)c0 * 128;
        uint4 kw0 = *(const uint4*)(r0 + h * 8);
        uint4 vw0 = *(const uint4*)(r0 + 64 + h * 8);
        float p0 = __expf(DOT8(kw0) * inv_scale);
        s += p0;
        ACC8(p0, vw0)
    }

    float inv = 1.f / (s + 1e-8f);
    *(uint4*)&aggb[(size_t)n * 64 + h * 8] = make_uint4(
        pkbf16(acc[0] * inv, acc[1] * inv), pkbf16(acc[2] * inv, acc[3] * inv),
        pkbf16(acc[4] * inv, acc[5] * inv), pkbf16(acc[6] * inv, acc[7] * inv));
}

// ---------------------------------------------------------------------------
// K7: output projection via MFMA. B-fragments load DIRECTLY from bf16 aggb.
// ---------------------------------------------------------------------------
__global__ __launch_bounds__(256) void out_kernel(
    const ushort_t* __restrict__ aggb, const ushort_t* __restrict__ Wto,
    const float* __restrict__ bo, float* __restrict__ out)
{
    int tid = threadIdx.x;
    int lane = tid & 63;
    int w = tid >> 6;
    int node = blockIdx.x * 64 + w * 16 + (lane & 15);
    int nclamp = node < N_NODES ? node : N_NODES - 1;
    int koff = (lane >> 4) * 8;

    U8 af[2];
    #pragma unroll
    for (int kh = 0; kh < 2; ++kh)
        af[kh].u = *(const uint4*)&aggb[(size_t)nclamp * 64 + kh * 32 + koff];

    f32x4 acc[4];
    #pragma unroll
    for (int ct = 0; ct < 4; ++ct) acc[ct] = (f32x4){0.f, 0.f, 0.f, 0.f};

    int colin = lane & 15;
    #pragma unroll
    for (int ct = 0; ct < 4; ++ct) {
        const ushort_t* wb = &Wto[(ct * 16 + colin) * 64 + koff];
        #pragma unroll
        for (int kh = 0; kh < 2; ++kh) {
            U8 wf;
            wf.u = *(const uint4*)(wb + kh * 32);
            acc[ct] = __builtin_amdgcn_mfma_f32_16x16x32_bf16(
                wf.b, af[kh].b, acc[ct], 0, 0, 0);
        }
    }

    if (node < N_NODES) {
        int wc4 = (lane >> 4) * 4;
        #pragma unroll
        for (int ct = 0; ct < 4; ++ct) {
            int wc = ct * 16 + wc4;
            float4 ob = *(const float4*)&bo[wc];
            f32x4 a = acc[ct];
            *(float4*)&out[(size_t)node * 64 + wc] =
                make_float4(a[0] + ob.x, a[1] + ob.y, a[2] + ob.z, a[3] + ob.w);
        }
    }
}

extern "C" void kernel_launch(void* const* d_in, const int* in_sizes, int n_in,
                              void* d_out, int out_size, void* d_ws, size_t ws_size,
                              hipStream_t stream)
{
    const float* x  = (const float*)d_in[0];
    const int*   ei = (const int*)  d_in[1];   // [2*E] flattened: row then col
    const float* Wq = (const float*)d_in[2];
    const float* bq = (const float*)d_in[3];
    const float* Wk = (const float*)d_in[4];
    const float* bk = (const float*)d_in[5];
    const float* Wv = (const float*)d_in[6];
    const float* bv = (const float*)d_in[7];
    const float* Wo = (const float*)d_in[8];
    const float* bo = (const float*)d_in[9];
    float* out = (float*)d_out;

    float* Q = (float*)d_ws;                               // N*64 f32           25.6 MB
    ushort_t* KVb = (ushort_t*)(Q + (size_t)N_NODES * 64); // N*128 bf16         25.6 MB
    ushort_t* aggb = KVb + (size_t)N_NODES * 128;          // N*64 bf16          12.8 MB
    int* deg    = (int*)(aggb + (size_t)N_NODES * 64);
    int* start  = deg + N_NODES;
    int* cursor = start + N_NODES;                         // 512 ints
    unsigned int* pairs = (unsigned int*)(cursor + 512);   // NBUCKETS*BCAP (elist aliases)
    ushort_t* Wt = (ushort_t*)(pairs + (size_t)NBUCKETS * BCAP);  // 4*64*64 bf16

    wtrans_kernel<<<1, 256, 0, stream>>>(Wq, Wk, Wv, Wo, Wt, cursor);
    qkv_kernel<<<NPROJ_BLOCKS, 256, 0, stream>>>(x, Wt, bq, bk, bv, Q, KVb);
    scatter_kernel<<<SCAT_BLOCKS, 1024, 0, stream>>>(ei, cursor, pairs);
    csr_build_kernel<<<NBUCKETS, 256, 0, stream>>>(pairs, cursor, deg, start);
    agg_kernel<<<3125, 256, 0, stream>>>(Q, KVb, start, deg, (const int*)pairs, aggb);
    out_kernel<<<NPROJ_BLOCKS, 256, 0, stream>>>(aggb, Wt + 3 * 4096, bo, out);
}

// Round 17
// 146.300 us; speedup vs baseline: 1.0892x; 1.0124x over previous
//
#include <hip/hip_runtime.h>
#include <hip/hip_bf16.h>
#include <math.h>

#define N_NODES 100000
#define N_EDGES 1600000
#define BUCKET_SHIFT 8
#define NBUCKETS ((N_NODES + 255) >> 8)      // 391 buckets of 256 nodes
#define BCAP 6144                            // mean 4096, sigma ~64 -> 32 sigma margin
#define NPROJ_BLOCKS ((N_NODES + 63) / 64)   // 1563 (64 nodes/block, 16/wave)
#define SCAT_BLOCKS ((N_EDGES / 4 + 2047) / 2048)  // 196 (8192 edges/block)
#define NCHUNKS 1563                         // agg 64-node chunks

typedef unsigned short ushort_t;
typedef __attribute__((ext_vector_type(8))) short bf16x8;   // 8 bf16 in 4 VGPRs
typedef __attribute__((ext_vector_type(4))) float f32x4;

union U8 { uint4 u; bf16x8 b; };

// pack two fp32 -> one uint of 2 bf16 (RTN-even) via compiler-lowered cvt_pk
__device__ inline unsigned pkbf16(float lo, float hi) {
    __hip_bfloat162 h = __float22bfloat162_rn(make_float2(lo, hi));
    return *reinterpret_cast<unsigned*>(&h);
}
__device__ inline float blo(unsigned w) { return __uint_as_float(w << 16); }
__device__ inline float bhi(unsigned w) { return __uint_as_float(w & 0xFFFF0000u); }

// ---------------------------------------------------------------------------
// K0: one-time prep. Transpose Wq/Wk/Wv/Wo (fp32 row-major [k][col]) into
// bf16 Wt[mat][col][k]. Also zeroes bucket cursors.
// ---------------------------------------------------------------------------
__global__ __launch_bounds__(256) void wtrans_kernel(
    const float* __restrict__ Wq, const float* __restrict__ Wk,
    const float* __restrict__ Wv, const float* __restrict__ Wo,
    ushort_t* __restrict__ Wt, int* __restrict__ cursor)
{
    int t = threadIdx.x;
    for (int i = t; i < 512; i += 256) cursor[i] = 0;
    int c = t & 63;
    int k0 = (t >> 6) * 16;
    const float* srcs[4] = {Wq, Wk, Wv, Wo};
    #pragma unroll
    for (int m = 0; m < 4; ++m) {
        const float* Wsrc = srcs[m];
        ushort_t* dst = Wt + m * 4096;
        unsigned p[8];
        #pragma unroll
        for (int j = 0; j < 8; ++j) {
            float lo = Wsrc[(k0 + 2 * j) * 64 + c];
            float hi = Wsrc[(k0 + 2 * j + 1) * 64 + c];
            p[j] = pkbf16(lo, hi);
        }
        *(uint4*)&dst[c * 64 + k0]     = make_uint4(p[0], p[1], p[2], p[3]);
        *(uint4*)&dst[c * 64 + k0 + 8] = make_uint4(p[4], p[5], p[6], p[7]);
    }
}

// ---------------------------------------------------------------------------
// K1: Q/KV projection via MFMA 16x16x32 bf16 (swapped operands; see R13).
// Q now stored BF16 (Qb). K/V stored in two half-head tables:
//   KVlo[n][64] = K(h0..3) 32 bf16 | V(h0..3) 32 bf16   (128 B row, 2 lines)
//   KVhi[n][64] = same for heads 4..7
// so agg waves gather only a 12.8 MB table (halves the compulsory per-XCD
// L2-miss footprint vs a 256 B row).
// ---------------------------------------------------------------------------
__global__ __launch_bounds__(256) void qkv_kernel(
    const float* __restrict__ x, const ushort_t* __restrict__ Wt,
    const float* __restrict__ bq, const float* __restrict__ bk,
    const float* __restrict__ bv,
    ushort_t* __restrict__ Qb, ushort_t* __restrict__ KVlo,
    ushort_t* __restrict__ KVhi)
{
    int tid = threadIdx.x;
    int lane = tid & 63;
    int w = tid >> 6;
    int node = blockIdx.x * 64 + w * 16 + (lane & 15);
    int nclamp = node < N_NODES ? node : N_NODES - 1;
    int koff = (lane >> 4) * 8;

    U8 xf[2];
    #pragma unroll
    for (int kh = 0; kh < 2; ++kh) {
        const float* xb = &x[(size_t)nclamp * 64 + kh * 32 + koff];
        float4 a0 = *(const float4*)xb;
        float4 a1 = *(const float4*)(xb + 4);
        unsigned* xp = (unsigned*)&xf[kh];
        xp[0] = pkbf16(a0.x, a0.y); xp[1] = pkbf16(a0.z, a0.w);
        xp[2] = pkbf16(a1.x, a1.y); xp[3] = pkbf16(a1.z, a1.w);
    }

    f32x4 acc[3][4];
    #pragma unroll
    for (int m = 0; m < 3; ++m)
        #pragma unroll
        for (int ct = 0; ct < 4; ++ct)
            acc[m][ct] = (f32x4){0.f, 0.f, 0.f, 0.f};

    int colin = lane & 15;
    #pragma unroll
    for (int m = 0; m < 3; ++m) {
        const ushort_t* Wm = Wt + m * 4096;
        #pragma unroll
        for (int ct = 0; ct < 4; ++ct) {
            const ushort_t* wb = &Wm[(ct * 16 + colin) * 64 + koff];
            #pragma unroll
            for (int kh = 0; kh < 2; ++kh) {
                U8 wf;
                wf.u = *(const uint4*)(wb + kh * 32);
                acc[m][ct] = __builtin_amdgcn_mfma_f32_16x16x32_bf16(
                    wf.b, xf[kh].b, acc[m][ct], 0, 0, 0);
            }
        }
    }

    if (node < N_NODES) {
        int wc4 = (lane >> 4) * 4;
        #pragma unroll
        for (int ct = 0; ct < 4; ++ct) {
            int wc = ct * 16 + wc4;        // output col: head = wc>>3, dim = wc&7
            float4 qb = *(const float4*)&bq[wc];
            f32x4 a = acc[0][ct];
            *(uint2*)&Qb[(size_t)node * 64 + wc] =
                make_uint2(pkbf16(a[0] + qb.x, a[1] + qb.y),
                           pkbf16(a[2] + qb.z, a[3] + qb.w));
            int hh = wc >> 3;
            ushort_t* kvdst = (hh < 4 ? KVlo : KVhi)
                            + (size_t)node * 64 + (hh & 3) * 8 + (wc & 7);
            float4 kb = *(const float4*)&bk[wc];
            f32x4 k = acc[1][ct];
            *(uint2*)kvdst =
                make_uint2(pkbf16(k[0] + kb.x, k[1] + kb.y),
                           pkbf16(k[2] + kb.z, k[3] + kb.w));
            float4 vb = *(const float4*)&bv[wc];
            f32x4 v = acc[2][ct];
            *(uint2*)(kvdst + 32) =
                make_uint2(pkbf16(v[0] + vb.x, v[1] + vb.y),
                           pkbf16(v[2] + vb.z, v[3] + vb.w));
        }
    }
}

// ---------------------------------------------------------------------------
// Pass 1: bucket scatter, 1024 threads x 8192 edges per block (196 blocks).
// ---------------------------------------------------------------------------
__global__ __launch_bounds__(1024) void scatter_kernel(
    const int* __restrict__ ei, int* __restrict__ cursor,
    unsigned int* __restrict__ pairs)
{
    __shared__ int hist[NBUCKETS];
    __shared__ int bbs[NBUCKETS];
    int t = threadIdx.x;
    for (int i = t; i < NBUCKETS; i += 1024) hist[i] = 0;
    __syncthreads();

    const int4* r4 = (const int4*)ei;
    const int4* c4 = (const int4*)(ei + N_EDGES);
    int ia = blockIdx.x * 2048 + t;
    int ib = ia + 1024;
    bool va = (ia < N_EDGES / 4), vb = (ib < N_EDGES / 4);
    int4 rva = va ? r4[ia] : make_int4(0, 0, 0, 0);
    int4 cva = va ? c4[ia] : make_int4(0, 0, 0, 0);
    int4 rvb = vb ? r4[ib] : make_int4(0, 0, 0, 0);
    int4 cvb = vb ? c4[ib] : make_int4(0, 0, 0, 0);

    int rr[8], cc[8];
    rr[0] = rva.x; rr[1] = rva.y; rr[2] = rva.z; rr[3] = rva.w;
    rr[4] = rvb.x; rr[5] = rvb.y; rr[6] = rvb.z; rr[7] = rvb.w;
    cc[0] = cva.x; cc[1] = cva.y; cc[2] = cva.z; cc[3] = cva.w;
    cc[4] = cvb.x; cc[5] = cvb.y; cc[6] = cvb.z; cc[7] = cvb.w;

    int bkt[8], rnk[8];
    unsigned pk[8];
    #pragma unroll
    for (int j = 0; j < 8; ++j) {
        bool v = (j < 4) ? va : vb;
        int b = rr[j] >> BUCKET_SHIFT;
        bkt[j] = b;
        rnk[j] = v ? atomicAdd(&hist[b], 1) : 0;
        pk[j] = ((unsigned)(rr[j] & 255) << 17) | (unsigned)cc[j];
    }
    __syncthreads();
    for (int i = t; i < NBUCKETS; i += 1024) {
        int h = hist[i];
        if (h) bbs[i] = i * BCAP + atomicAdd(&cursor[i], h);
    }
    __syncthreads();
    #pragma unroll
    for (int j = 0; j < 8; ++j) {
        bool v = (j < 4) ? va : vb;
        if (v) pairs[bbs[bkt[j]] + rnk[j]] = pk[j];
    }
}

// ---------------------------------------------------------------------------
// Pass 2: one block per bucket. Stage pairs in LDS, 256-bin histogram + scan
// -> deg/start; write ordered col ids back IN PLACE (elist aliases pairs,
// padded at b*BCAP). start[n] = b*BCAP + excl.
// ---------------------------------------------------------------------------
__global__ __launch_bounds__(256) void csr_build_kernel(
    unsigned int* __restrict__ pairs, const int* __restrict__ cursor,
    int* __restrict__ deg, int* __restrict__ start)
{
    __shared__ unsigned int lp[BCAP];        // 24 KB
    __shared__ int hist[256], scn[256];
    int b = blockIdx.x, t = threadIdx.x;
    int cnt = cursor[b];
    unsigned int* bp = pairs + (size_t)b * BCAP;

    for (int i = t; i < cnt; i += 256) lp[i] = bp[i];
    hist[t] = 0;
    __syncthreads();
    for (int i = t; i < cnt; i += 256) atomicAdd(&hist[lp[i] >> 17], 1);
    __syncthreads();

    int h = hist[t];
    scn[t] = h;
    __syncthreads();
    for (int off = 1; off < 256; off <<= 1) {
        int u = (t >= off) ? scn[t - off] : 0;
        __syncthreads();
        scn[t] += u;
        __syncthreads();
    }
    int excl = scn[t] - h;
    int node = (b << BUCKET_SHIFT) + t;
    if (node < N_NODES) { deg[node] = h; start[node] = b * BCAP + excl; }
    hist[t] = excl;                          // reuse as local cursor
    __syncthreads();
    for (int i = t; i < cnt; i += 256) {
        unsigned p = lp[i];
        int pos = atomicAdd(&hist[p >> 17], 1);
        bp[pos] = p & 0x1FFFFu;              // ordered col id, in place
    }
}

// ---------------------------------------------------------------------------
// K6: per-node softmax aggregation over HALF-HEAD tables. Wave = 16 nodes x
// 4 heads (lane = (node-slot = lane>>2, h2 = lane&3)); wave's half chosen by
// blockIdx so halves group onto XCD sets (blockIdx%8: 0-3 -> lo, 4-7 -> hi).
// Each XCD then touches only one 12.8 MB table (2-line rows) -> compulsory
// L2-miss footprint ~halves. s/acc lane-local, zero cross-lane ops, ILP-2.
// ---------------------------------------------------------------------------
#define DOT8H(KW) (blo(KW.x) * q0 + bhi(KW.x) * q1                            \
                 + blo(KW.y) * q2 + bhi(KW.y) * q3                            \
                 + blo(KW.z) * q4 + bhi(KW.z) * q5                            \
                 + blo(KW.w) * q6 + bhi(KW.w) * q7)

#define ACC8H(P, VW)                                                          \
    acc[0] = fmaf(P, blo(VW.x), acc[0]);                                      \
    acc[1] = fmaf(P, bhi(VW.x), acc[1]);                                      \
    acc[2] = fmaf(P, blo(VW.y), acc[2]);                                      \
    acc[3] = fmaf(P, bhi(VW.y), acc[3]);                                      \
    acc[4] = fmaf(P, blo(VW.z), acc[4]);                                      \
    acc[5] = fmaf(P, bhi(VW.z), acc[5]);                                      \
    acc[6] = fmaf(P, blo(VW.w), acc[6]);                                      \
    acc[7] = fmaf(P, bhi(VW.w), acc[7]);

__global__ __launch_bounds__(256) void agg_kernel(
    const ushort_t* __restrict__ Qb, const ushort_t* __restrict__ KVlo,
    const ushort_t* __restrict__ KVhi,
    const int* __restrict__ start, const int* __restrict__ deg,
    const int* __restrict__ elist, ushort_t* __restrict__ aggb)
{
    int bid = blockIdx.x;
    int grp = bid & 7;
    int half = grp >> 2;                     // XCDs 0-3 -> lo, 4-7 -> hi
    int k = (bid >> 3) * 4 + (grp & 3);      // 64-node chunk id
    if (k >= NCHUNKS) return;

    int tid = threadIdx.x;
    int lane = tid & 63;
    int ns = lane >> 2;                      // node slot 0..15
    int h2 = lane & 3;                       // head within half
    int n = k * 64 + (tid >> 6) * 16 + ns;
    bool valid = n < N_NODES;
    int nc = valid ? n : N_NODES - 1;

    int d = deg[nc];
    int st = start[nc];
    const ushort_t* KV = half ? KVhi : KVlo;

    uint4 qw = *(const uint4*)&Qb[(size_t)nc * 64 + (half * 4 + h2) * 8];
    float q0 = blo(qw.x), q1 = bhi(qw.x), q2 = blo(qw.y), q3 = bhi(qw.y);
    float q4 = blo(qw.z), q5 = bhi(qw.z), q6 = blo(qw.w), q7 = bhi(qw.w);

    const float inv_scale = 0.35355339059327373f;  // 1/sqrt(8)
    float s = 0.f;
    float acc[8] = {0.f, 0.f, 0.f, 0.f, 0.f, 0.f, 0.f, 0.f};

    int j = 0;
    for (; j + 2 <= d; j += 2) {
        int c0 = elist[st + j];
        int c1 = elist[st + j + 1];
        const ushort_t* r0 = KV + (size_t)c0 * 64 + h2 * 8;
        const ushort_t* r1 = KV + (size_t)c1 * 64 + h2 * 8;
        uint4 kw0 = *(const uint4*)r0;
        uint4 kw1 = *(const uint4*)r1;
        uint4 vw0 = *(const uint4*)(r0 + 32);
        uint4 vw1 = *(const uint4*)(r1 + 32);
        float p0 = __expf(DOT8H(kw0) * inv_scale);
        float p1 = __expf(DOT8H(kw1) * inv_scale);
        s += p0 + p1;
        ACC8H(p0, vw0)
        ACC8H(p1, vw1)
    }
    if (j < d) {
        int c0 = elist[st + j];
        const ushort_t* r0 = KV + (size_t)c0 * 64 + h2 * 8;
        uint4 kw0 = *(const uint4*)r0;
        uint4 vw0 = *(const uint4*)(r0 + 32);
        float p0 = __expf(DOT8H(kw0) * inv_scale);
        s += p0;
        ACC8H(p0, vw0)
    }

    if (valid) {
        float inv = 1.f / (s + 1e-8f);
        *(uint4*)&aggb[(size_t)n * 64 + (half * 4 + h2) * 8] = make_uint4(
            pkbf16(acc[0] * inv, acc[1] * inv), pkbf16(acc[2] * inv, acc[3] * inv),
            pkbf16(acc[4] * inv, acc[5] * inv), pkbf16(acc[6] * inv, acc[7] * inv));
    }
}

// ---------------------------------------------------------------------------
// K7: output projection via MFMA. B-fragments load DIRECTLY from bf16 aggb.
// ---------------------------------------------------------------------------
__global__ __launch_bounds__(256) void out_kernel(
    const ushort_t* __restrict__ aggb, const ushort_t* __restrict__ Wto,
    const float* __restrict__ bo, float* __restrict__ out)
{
    int tid = threadIdx.x;
    int lane = tid & 63;
    int w = tid >> 6;
    int node = blockIdx.x * 64 + w * 16 + (lane & 15);
    int nclamp = node < N_NODES ? node : N_NODES - 1;
    int koff = (lane >> 4) * 8;

    U8 af[2];
    #pragma unroll
    for (int kh = 0; kh < 2; ++kh)
        af[kh].u = *(const uint4*)&aggb[(size_t)nclamp * 64 + kh * 32 + koff];

    f32x4 acc[4];
    #pragma unroll
    for (int ct = 0; ct < 4; ++ct) acc[ct] = (f32x4){0.f, 0.f, 0.f, 0.f};

    int colin = lane & 15;
    #pragma unroll
    for (int ct = 0; ct < 4; ++ct) {
        const ushort_t* wb = &Wto[(ct * 16 + colin) * 64 + koff];
        #pragma unroll
        for (int kh = 0; kh < 2; ++kh) {
            U8 wf;
            wf.u = *(const uint4*)(wb + kh * 32);
            acc[ct] = __builtin_amdgcn_mfma_f32_16x16x32_bf16(
                wf.b, af[kh].b, acc[ct], 0, 0, 0);
        }
    }

    if (node < N_NODES) {
        int wc4 = (lane >> 4) * 4;
        #pragma unroll
        for (int ct = 0; ct < 4; ++ct) {
            int wc = ct * 16 + wc4;
            float4 ob = *(const float4*)&bo[wc];
            f32x4 a = acc[ct];
            *(float4*)&out[(size_t)node * 64 + wc] =
                make_float4(a[0] + ob.x, a[1] + ob.y, a[2] + ob.z, a[3] + ob.w);
        }
    }
}

extern "C" void kernel_launch(void* const* d_in, const int* in_sizes, int n_in,
                              void* d_out, int out_size, void* d_ws, size_t ws_size,
                              hipStream_t stream)
{
    const float* x  = (const float*)d_in[0];
    const int*   ei = (const int*)  d_in[1];   // [2*E] flattened: row then col
    const float* Wq = (const float*)d_in[2];
    const float* bq = (const float*)d_in[3];
    const float* Wk = (const float*)d_in[4];
    const float* bk = (const float*)d_in[5];
    const float* Wv = (const float*)d_in[6];
    const float* bv = (const float*)d_in[7];
    const float* Wo = (const float*)d_in[8];
    const float* bo = (const float*)d_in[9];
    float* out = (float*)d_out;

    ushort_t* Qb   = (ushort_t*)d_ws;                      // N*64 bf16   12.8 MB
    ushort_t* KVlo = Qb + (size_t)N_NODES * 64;            // N*64 bf16   12.8 MB
    ushort_t* KVhi = KVlo + (size_t)N_NODES * 64;          // N*64 bf16   12.8 MB
    ushort_t* aggb = KVhi + (size_t)N_NODES * 64;          // N*64 bf16   12.8 MB
    int* deg    = (int*)(aggb + (size_t)N_NODES * 64);
    int* start  = deg + N_NODES;
    int* cursor = start + N_NODES;                         // 512 ints
    unsigned int* pairs = (unsigned int*)(cursor + 512);   // NBUCKETS*BCAP (elist aliases)
    ushort_t* Wt = (ushort_t*)(pairs + (size_t)NBUCKETS * BCAP);  // 4*64*64 bf16

    wtrans_kernel<<<1, 256, 0, stream>>>(Wq, Wk, Wv, Wo, Wt, cursor);
    qkv_kernel<<<NPROJ_BLOCKS, 256, 0, stream>>>(x, Wt, bq, bk, bv, Qb, KVlo, KVhi);
    scatter_kernel<<<SCAT_BLOCKS, 1024, 0, stream>>>(ei, cursor, pairs);
    csr_build_kernel<<<NBUCKETS, 256, 0, stream>>>(pairs, cursor, deg, start);
    agg_kernel<<<((NCHUNKS + 3) / 4) * 8, 256, 0, stream>>>(
        Qb, KVlo, KVhi, start, deg, (const int*)pairs, aggb);
    out_kernel<<<NPROJ_BLOCKS, 256, 0, stream>>>(aggb, Wt + 3 * 4096, bo, out);
}

// Round 18
// 142.481 us; speedup vs baseline: 1.1183x; 1.0268x over previous
//
#include <hip/hip_runtime.h>
#include <hip/hip_bf16.h>
#include <math.h>

#define N_NODES 100000
#define N_EDGES 1600000
#define BUCKET_SHIFT 8
#define NBUCKETS ((N_NODES + 255) >> 8)      // 391 buckets of 256 nodes
#define BCAP 6144                            // mean 4096, sigma ~64 -> 32 sigma margin
#define NPROJ_BLOCKS ((N_NODES + 63) / 64)   // 1563 (64 nodes/block, 16/wave)
#define SCAT_BLOCKS ((N_EDGES / 4 + 2047) / 2048)  // 196 (8192 edges/block)
#define NCHUNKS 1563                         // agg 64-node chunks

typedef unsigned short ushort_t;
typedef __attribute__((ext_vector_type(8))) short bf16x8;   // 8 bf16 in 4 VGPRs
typedef __attribute__((ext_vector_type(4))) float f32x4;

union U8 { uint4 u; bf16x8 b; };

// pack two fp32 -> one uint of 2 bf16 (RTN-even) via compiler-lowered cvt_pk
__device__ inline unsigned pkbf16(float lo, float hi) {
    __hip_bfloat162 h = __float22bfloat162_rn(make_float2(lo, hi));
    return *reinterpret_cast<unsigned*>(&h);
}
__device__ inline float blo(unsigned w) { return __uint_as_float(w << 16); }
__device__ inline float bhi(unsigned w) { return __uint_as_float(w & 0xFFFF0000u); }

// ---------------------------------------------------------------------------
// K0: one-time prep. Transpose Wq/Wk/Wv/Wo (fp32 row-major [k][col]) into
// bf16 Wt[mat][col][k]. Also zeroes bucket cursors.
// ---------------------------------------------------------------------------
__global__ __launch_bounds__(256) void wtrans_kernel(
    const float* __restrict__ Wq, const float* __restrict__ Wk,
    const float* __restrict__ Wv, const float* __restrict__ Wo,
    ushort_t* __restrict__ Wt, int* __restrict__ cursor)
{
    int t = threadIdx.x;
    for (int i = t; i < 512; i += 256) cursor[i] = 0;
    int c = t & 63;
    int k0 = (t >> 6) * 16;
    const float* srcs[4] = {Wq, Wk, Wv, Wo};
    #pragma unroll
    for (int m = 0; m < 4; ++m) {
        const float* Wsrc = srcs[m];
        ushort_t* dst = Wt + m * 4096;
        unsigned p[8];
        #pragma unroll
        for (int j = 0; j < 8; ++j) {
            float lo = Wsrc[(k0 + 2 * j) * 64 + c];
            float hi = Wsrc[(k0 + 2 * j + 1) * 64 + c];
            p[j] = pkbf16(lo, hi);
        }
        *(uint4*)&dst[c * 64 + k0]     = make_uint4(p[0], p[1], p[2], p[3]);
        *(uint4*)&dst[c * 64 + k0 + 8] = make_uint4(p[4], p[5], p[6], p[7]);
    }
}

// ---------------------------------------------------------------------------
// K1: Q/KV projection via MFMA 16x16x32 bf16 (swapped operands; see R13).
// Q stored BF16 (Qb). K/V in two half-head tables (KVlo: heads 0-3,
// KVhi: heads 4-7), 128 B rows.
// ---------------------------------------------------------------------------
__global__ __launch_bounds__(256) void qkv_kernel(
    const float* __restrict__ x, const ushort_t* __restrict__ Wt,
    const float* __restrict__ bq, const float* __restrict__ bk,
    const float* __restrict__ bv,
    ushort_t* __restrict__ Qb, ushort_t* __restrict__ KVlo,
    ushort_t* __restrict__ KVhi)
{
    int tid = threadIdx.x;
    int lane = tid & 63;
    int w = tid >> 6;
    int node = blockIdx.x * 64 + w * 16 + (lane & 15);
    int nclamp = node < N_NODES ? node : N_NODES - 1;
    int koff = (lane >> 4) * 8;

    U8 xf[2];
    #pragma unroll
    for (int kh = 0; kh < 2; ++kh) {
        const float* xb = &x[(size_t)nclamp * 64 + kh * 32 + koff];
        float4 a0 = *(const float4*)xb;
        float4 a1 = *(const float4*)(xb + 4);
        unsigned* xp = (unsigned*)&xf[kh];
        xp[0] = pkbf16(a0.x, a0.y); xp[1] = pkbf16(a0.z, a0.w);
        xp[2] = pkbf16(a1.x, a1.y); xp[3] = pkbf16(a1.z, a1.w);
    }

    f32x4 acc[3][4];
    #pragma unroll
    for (int m = 0; m < 3; ++m)
        #pragma unroll
        for (int ct = 0; ct < 4; ++ct)
            acc[m][ct] = (f32x4){0.f, 0.f, 0.f, 0.f};

    int colin = lane & 15;
    #pragma unroll
    for (int m = 0; m < 3; ++m) {
        const ushort_t* Wm = Wt + m * 4096;
        #pragma unroll
        for (int ct = 0; ct < 4; ++ct) {
            const ushort_t* wb = &Wm[(ct * 16 + colin) * 64 + koff];
            #pragma unroll
            for (int kh = 0; kh < 2; ++kh) {
                U8 wf;
                wf.u = *(const uint4*)(wb + kh * 32);
                acc[m][ct] = __builtin_amdgcn_mfma_f32_16x16x32_bf16(
                    wf.b, xf[kh].b, acc[m][ct], 0, 0, 0);
            }
        }
    }

    if (node < N_NODES) {
        int wc4 = (lane >> 4) * 4;
        #pragma unroll
        for (int ct = 0; ct < 4; ++ct) {
            int wc = ct * 16 + wc4;        // output col: head = wc>>3, dim = wc&7
            float4 qb = *(const float4*)&bq[wc];
            f32x4 a = acc[0][ct];
            *(uint2*)&Qb[(size_t)node * 64 + wc] =
                make_uint2(pkbf16(a[0] + qb.x, a[1] + qb.y),
                           pkbf16(a[2] + qb.z, a[3] + qb.w));
            int hh = wc >> 3;
            ushort_t* kvdst = (hh < 4 ? KVlo : KVhi)
                            + (size_t)node * 64 + (hh & 3) * 8 + (wc & 7);
            float4 kb = *(const float4*)&bk[wc];
            f32x4 k = acc[1][ct];
            *(uint2*)kvdst =
                make_uint2(pkbf16(k[0] + kb.x, k[1] + kb.y),
                           pkbf16(k[2] + kb.z, k[3] + kb.w));
            float4 vb = *(const float4*)&bv[wc];
            f32x4 v = acc[2][ct];
            *(uint2*)(kvdst + 32) =
                make_uint2(pkbf16(v[0] + vb.x, v[1] + vb.y),
                           pkbf16(v[2] + vb.z, v[3] + vb.w));
        }
    }
}

// ---------------------------------------------------------------------------
// Pass 1: bucket scatter, 1024 threads x 8192 edges per block (196 blocks).
// ---------------------------------------------------------------------------
__global__ __launch_bounds__(1024) void scatter_kernel(
    const int* __restrict__ ei, int* __restrict__ cursor,
    unsigned int* __restrict__ pairs)
{
    __shared__ int hist[NBUCKETS];
    __shared__ int bbs[NBUCKETS];
    int t = threadIdx.x;
    for (int i = t; i < NBUCKETS; i += 1024) hist[i] = 0;
    __syncthreads();

    const int4* r4 = (const int4*)ei;
    const int4* c4 = (const int4*)(ei + N_EDGES);
    int ia = blockIdx.x * 2048 + t;
    int ib = ia + 1024;
    bool va = (ia < N_EDGES / 4), vb = (ib < N_EDGES / 4);
    int4 rva = va ? r4[ia] : make_int4(0, 0, 0, 0);
    int4 cva = va ? c4[ia] : make_int4(0, 0, 0, 0);
    int4 rvb = vb ? r4[ib] : make_int4(0, 0, 0, 0);
    int4 cvb = vb ? c4[ib] : make_int4(0, 0, 0, 0);

    int rr[8], cc[8];
    rr[0] = rva.x; rr[1] = rva.y; rr[2] = rva.z; rr[3] = rva.w;
    rr[4] = rvb.x; rr[5] = rvb.y; rr[6] = rvb.z; rr[7] = rvb.w;
    cc[0] = cva.x; cc[1] = cva.y; cc[2] = cva.z; cc[3] = cva.w;
    cc[4] = cvb.x; cc[5] = cvb.y; cc[6] = cvb.z; cc[7] = cvb.w;

    int bkt[8], rnk[8];
    unsigned pk[8];
    #pragma unroll
    for (int j = 0; j < 8; ++j) {
        bool v = (j < 4) ? va : vb;
        int b = rr[j] >> BUCKET_SHIFT;
        bkt[j] = b;
        rnk[j] = v ? atomicAdd(&hist[b], 1) : 0;
        pk[j] = ((unsigned)(rr[j] & 255) << 17) | (unsigned)cc[j];
    }
    __syncthreads();
    for (int i = t; i < NBUCKETS; i += 1024) {
        int h = hist[i];
        if (h) bbs[i] = i * BCAP + atomicAdd(&cursor[i], h);
    }
    __syncthreads();
    #pragma unroll
    for (int j = 0; j < 8; ++j) {
        bool v = (j < 4) ? va : vb;
        if (v) pairs[bbs[bkt[j]] + rnk[j]] = pk[j];
    }
}

// ---------------------------------------------------------------------------
// Pass 2: one block per bucket. Stage pairs in LDS; 1024-bin histogram keyed
// (node_local<<2 | col_chunk) with col_chunk = col/25000 -> each node's edge
// list comes out ORDERED BY COL-CHUNK (cache blocking: agg's gather stream
// then concentrates in one 3.2 MB L2-resident chunk at a time). Scan via
// shfl wave-scan (2 barriers, was 16). Writes ordered col ids back IN PLACE.
// start[n] = b*BCAP + excl; deg[n] = sum of its 4 chunk bins.
// ---------------------------------------------------------------------------
__global__ __launch_bounds__(256) void csr_build_kernel(
    unsigned int* __restrict__ pairs, const int* __restrict__ cursor,
    int* __restrict__ deg, int* __restrict__ start)
{
    __shared__ unsigned int lp[BCAP];        // 24 KB
    __shared__ int hist[1024];               // 4 KB
    __shared__ int wsum[4];
    int b = blockIdx.x, t = threadIdx.x;
    int cnt = cursor[b];
    unsigned int* bp = pairs + (size_t)b * BCAP;

    for (int i = t; i < cnt; i += 256) lp[i] = bp[i];
    for (int i = t; i < 1024; i += 256) hist[i] = 0;
    __syncthreads();
    for (int i = t; i < cnt; i += 256) {
        unsigned p = lp[i];
        unsigned col = p & 0x1FFFFu;
        int key = (int)((p >> 17) << 2) | (int)(col / 25000u);
        atomicAdd(&hist[key], 1);
    }
    __syncthreads();

    // thread t owns node-bin t (4 chunk bins)
    int h0 = hist[4 * t], h1 = hist[4 * t + 1], h2 = hist[4 * t + 2], h3 = hist[4 * t + 3];
    int local = h0 + h1 + h2 + h3;
    int lane = t & 63, w = t >> 6;
    int inc = local;
    #pragma unroll
    for (int off = 1; off < 64; off <<= 1) {
        int u = __shfl_up(inc, off);
        if (lane >= off) inc += u;
    }
    if (lane == 63) wsum[w] = inc;
    __syncthreads();
    int woff = 0;
    for (int i = 0; i < w; ++i) woff += wsum[i];
    int excl = woff + inc - local;
    int node = (b << BUCKET_SHIFT) + t;
    if (node < N_NODES) { deg[node] = local; start[node] = b * BCAP + excl; }
    __syncthreads();                         // hist reads done before overwrite
    hist[4 * t]     = excl;
    hist[4 * t + 1] = excl + h0;
    hist[4 * t + 2] = excl + h0 + h1;
    hist[4 * t + 3] = excl + h0 + h1 + h2;
    __syncthreads();
    for (int i = t; i < cnt; i += 256) {
        unsigned p = lp[i];
        unsigned col = p & 0x1FFFFu;
        int key = (int)((p >> 17) << 2) | (int)(col / 25000u);
        int pos = atomicAdd(&hist[key], 1);
        bp[pos] = col;
    }
}

// ---------------------------------------------------------------------------
// K6: per-node softmax aggregation over HALF-HEAD tables (R17). Edge lists
// are col-chunk-ordered (csr) so the gather working set is ~3.2 MB at a
// time -> L2-resident. s/acc lane-local, zero cross-lane ops, ILP-2.
// ---------------------------------------------------------------------------
#define DOT8H(KW) (blo(KW.x) * q0 + bhi(KW.x) * q1                            \
                 + blo(KW.y) * q2 + bhi(KW.y) * q3                            \
                 + blo(KW.z) * q4 + bhi(KW.z) * q5                            \
                 + blo(KW.w) * q6 + bhi(KW.w) * q7)

#define ACC8H(P, VW)                                                          \
    acc[0] = fmaf(P, blo(VW.x), acc[0]);                                      \
    acc[1] = fmaf(P, bhi(VW.x), acc[1]);                                      \
    acc[2] = fmaf(P, blo(VW.y), acc[2]);                                      \
    acc[3] = fmaf(P, bhi(VW.y), acc[3]);                                      \
    acc[4] = fmaf(P, blo(VW.z), acc[4]);                                      \
    acc[5] = fmaf(P, bhi(VW.z), acc[5]);                                      \
    acc[6] = fmaf(P, blo(VW.w), acc[6]);                                      \
    acc[7] = fmaf(P, bhi(VW.w), acc[7]);

__global__ __launch_bounds__(256) void agg_kernel(
    const ushort_t* __restrict__ Qb, const ushort_t* __restrict__ KVlo,
    const ushort_t* __restrict__ KVhi,
    const int* __restrict__ start, const int* __restrict__ deg,
    const int* __restrict__ elist, ushort_t* __restrict__ aggb)
{
    int bid = blockIdx.x;
    int grp = bid & 7;
    int half = grp >> 2;                     // XCDs 0-3 -> lo, 4-7 -> hi
    int k = (bid >> 3) * 4 + (grp & 3);      // 64-node chunk id
    if (k >= NCHUNKS) return;

    int tid = threadIdx.x;
    int lane = tid & 63;
    int ns = lane >> 2;                      // node slot 0..15
    int h2 = lane & 3;                       // head within half
    int n = k * 64 + (tid >> 6) * 16 + ns;
    bool valid = n < N_NODES;
    int nc = valid ? n : N_NODES - 1;

    int d = deg[nc];
    int st = start[nc];
    const ushort_t* KV = half ? KVhi : KVlo;

    uint4 qw = *(const uint4*)&Qb[(size_t)nc * 64 + (half * 4 + h2) * 8];
    float q0 = blo(qw.x), q1 = bhi(qw.x), q2 = blo(qw.y), q3 = bhi(qw.y);
    float q4 = blo(qw.z), q5 = bhi(qw.z), q6 = blo(qw.w), q7 = bhi(qw.w);

    const float inv_scale = 0.35355339059327373f;  // 1/sqrt(8)
    float s = 0.f;
    float acc[8] = {0.f, 0.f, 0.f, 0.f, 0.f, 0.f, 0.f, 0.f};

    int j = 0;
    for (; j + 2 <= d; j += 2) {
        int c0 = elist[st + j];
        int c1 = elist[st + j + 1];
        const ushort_t* r0 = KV + (size_t)c0 * 64 + h2 * 8;
        const ushort_t* r1 = KV + (size_t)c1 * 64 + h2 * 8;
        uint4 kw0 = *(const uint4*)r0;
        uint4 kw1 = *(const uint4*)r1;
        uint4 vw0 = *(const uint4*)(r0 + 32);
        uint4 vw1 = *(const uint4*)(r1 + 32);
        float p0 = __expf(DOT8H(kw0) * inv_scale);
        float p1 = __expf(DOT8H(kw1) * inv_scale);
        s += p0 + p1;
        ACC8H(p0, vw0)
        ACC8H(p1, vw1)
    }
    if (j < d) {
        int c0 = elist[st + j];
        const ushort_t* r0 = KV + (size_t)c0 * 64 + h2 * 8;
        uint4 kw0 = *(const uint4*)r0;
        uint4 vw0 = *(const uint4*)(r0 + 32);
        float p0 = __expf(DOT8H(kw0) * inv_scale);
        s += p0;
        ACC8H(p0, vw0)
    }

    if (valid) {
        float inv = 1.f / (s + 1e-8f);
        *(uint4*)&aggb[(size_t)n * 64 + (half * 4 + h2) * 8] = make_uint4(
            pkbf16(acc[0] * inv, acc[1] * inv), pkbf16(acc[2] * inv, acc[3] * inv),
            pkbf16(acc[4] * inv, acc[5] * inv), pkbf16(acc[6] * inv, acc[7] * inv));
    }
}

// ---------------------------------------------------------------------------
// K7: output projection via MFMA. B-fragments load DIRECTLY from bf16 aggb.
// ---------------------------------------------------------------------------
__global__ __launch_bounds__(256) void out_kernel(
    const ushort_t* __restrict__ aggb, const ushort_t* __restrict__ Wto,
    const float* __restrict__ bo, float* __restrict__ out)
{
    int tid = threadIdx.x;
    int lane = tid & 63;
    int w = tid >> 6;
    int node = blockIdx.x * 64 + w * 16 + (lane & 15);
    int nclamp = node < N_NODES ? node : N_NODES - 1;
    int koff = (lane >> 4) * 8;

    U8 af[2];
    #pragma unroll
    for (int kh = 0; kh < 2; ++kh)
        af[kh].u = *(const uint4*)&aggb[(size_t)nclamp * 64 + kh * 32 + koff];

    f32x4 acc[4];
    #pragma unroll
    for (int ct = 0; ct < 4; ++ct) acc[ct] = (f32x4){0.f, 0.f, 0.f, 0.f};

    int colin = lane & 15;
    #pragma unroll
    for (int ct = 0; ct < 4; ++ct) {
        const ushort_t* wb = &Wto[(ct * 16 + colin) * 64 + koff];
        #pragma unroll
        for (int kh = 0; kh < 2; ++kh) {
            U8 wf;
            wf.u = *(const uint4*)(wb + kh * 32);
            acc[ct] = __builtin_amdgcn_mfma_f32_16x16x32_bf16(
                wf.b, af[kh].b, acc[ct], 0, 0, 0);
        }
    }

    if (node < N_NODES) {
        int wc4 = (lane >> 4) * 4;
        #pragma unroll
        for (int ct = 0; ct < 4; ++ct) {
            int wc = ct * 16 + wc4;
            float4 ob = *(const float4*)&bo[wc];
            f32x4 a = acc[ct];
            *(float4*)&out[(size_t)node * 64 + wc] =
                make_float4(a[0] + ob.x, a[1] + ob.y, a[2] + ob.z, a[3] + ob.w);
        }
    }
}

extern "C" void kernel_launch(void* const* d_in, const int* in_sizes, int n_in,
                              void* d_out, int out_size, void* d_ws, size_t ws_size,
                              hipStream_t stream)
{
    const float* x  = (const float*)d_in[0];
    const int*   ei = (const int*)  d_in[1];   // [2*E] flattened: row then col
    const float* Wq = (const float*)d_in[2];
    const float* bq = (const float*)d_in[3];
    const float* Wk = (const float*)d_in[4];
    const float* bk = (const float*)d_in[5];
    const float* Wv = (const float*)d_in[6];
    const float* bv = (const float*)d_in[7];
    const float* Wo = (const float*)d_in[8];
    const float* bo = (const float*)d_in[9];
    float* out = (float*)d_out;

    ushort_t* Qb   = (ushort_t*)d_ws;                      // N*64 bf16   12.8 MB
    ushort_t* KVlo = Qb + (size_t)N_NODES * 64;            // N*64 bf16   12.8 MB
    ushort_t* KVhi = KVlo + (size_t)N_NODES * 64;          // N*64 bf16   12.8 MB
    ushort_t* aggb = KVhi + (size_t)N_NODES * 64;          // N*64 bf16   12.8 MB
    int* deg    = (int*)(aggb + (size_t)N_NODES * 64);
    int* start  = deg + N_NODES;
    int* cursor = start + N_NODES;                         // 512 ints
    unsigned int* pairs = (unsigned int*)(cursor + 512);   // NBUCKETS*BCAP (elist aliases)
    ushort_t* Wt = (ushort_t*)(pairs + (size_t)NBUCKETS * BCAP);  // 4*64*64 bf16

    wtrans_kernel<<<1, 256, 0, stream>>>(Wq, Wk, Wv, Wo, Wt, cursor);
    qkv_kernel<<<NPROJ_BLOCKS, 256, 0, stream>>>(x, Wt, bq, bk, bv, Qb, KVlo, KVhi);
    scatter_kernel<<<SCAT_BLOCKS, 1024, 0, stream>>>(ei, cursor, pairs);
    csr_build_kernel<<<NBUCKETS, 256, 0, stream>>>(pairs, cursor, deg, start);
    agg_kernel<<<((NCHUNKS + 3) / 4) * 8, 256, 0, stream>>>(
        Qb, KVlo, KVhi, start, deg, (const int*)pairs, aggb);
    out_kernel<<<NPROJ_BLOCKS, 256, 0, stream>>>(aggb, Wt + 3 * 4096, bo, out);
}

// Round 19
// 141.471 us; speedup vs baseline: 1.1263x; 1.0071x over previous
//
#include <hip/hip_runtime.h>
#include <hip/hip_bf16.h>
#include <math.h>

#define N_NODES 100000
#define N_EDGES 1600000
#define BUCKET_SHIFT 8
#define NBUCKETS ((N_NODES + 255) >> 8)      // 391 buckets of 256 nodes
#define BCAP 6144                            // mean 4096, sigma ~64 -> 32 sigma margin
#define NPROJ_BLOCKS ((N_NODES + 63) / 64)   // 1563 (64 nodes/block, 16/wave)
#define SCAT_BLOCKS ((N_EDGES / 4 + 2047) / 2048)  // 196 (8192 edges/block)
#define NCHUNKS 1563                         // agg 64-node chunks
#define CCHUNK 6250u                         // col-chunk width (16 chunks, 0.8 MB/half)

typedef unsigned short ushort_t;
typedef __attribute__((ext_vector_type(8))) short bf16x8;   // 8 bf16 in 4 VGPRs
typedef __attribute__((ext_vector_type(4))) float f32x4;

union U8 { uint4 u; bf16x8 b; };

// pack two fp32 -> one uint of 2 bf16 (RTN-even) via compiler-lowered cvt_pk
__device__ inline unsigned pkbf16(float lo, float hi) {
    __hip_bfloat162 h = __float22bfloat162_rn(make_float2(lo, hi));
    return *reinterpret_cast<unsigned*>(&h);
}
__device__ inline float blo(unsigned w) { return __uint_as_float(w << 16); }
__device__ inline float bhi(unsigned w) { return __uint_as_float(w & 0xFFFF0000u); }

// ---------------------------------------------------------------------------
// K0: one-time prep. Transpose Wq/Wk/Wv/Wo (fp32 row-major [k][col]) into
// bf16 Wt[mat][col][k]. Also zeroes bucket cursors.
// ---------------------------------------------------------------------------
__global__ __launch_bounds__(256) void wtrans_kernel(
    const float* __restrict__ Wq, const float* __restrict__ Wk,
    const float* __restrict__ Wv, const float* __restrict__ Wo,
    ushort_t* __restrict__ Wt, int* __restrict__ cursor)
{
    int t = threadIdx.x;
    for (int i = t; i < 512; i += 256) cursor[i] = 0;
    int c = t & 63;
    int k0 = (t >> 6) * 16;
    const float* srcs[4] = {Wq, Wk, Wv, Wo};
    #pragma unroll
    for (int m = 0; m < 4; ++m) {
        const float* Wsrc = srcs[m];
        ushort_t* dst = Wt + m * 4096;
        unsigned p[8];
        #pragma unroll
        for (int j = 0; j < 8; ++j) {
            float lo = Wsrc[(k0 + 2 * j) * 64 + c];
            float hi = Wsrc[(k0 + 2 * j + 1) * 64 + c];
            p[j] = pkbf16(lo, hi);
        }
        *(uint4*)&dst[c * 64 + k0]     = make_uint4(p[0], p[1], p[2], p[3]);
        *(uint4*)&dst[c * 64 + k0 + 8] = make_uint4(p[4], p[5], p[6], p[7]);
    }
}

// ---------------------------------------------------------------------------
// K1: Q/KV projection via MFMA 16x16x32 bf16 (swapped operands; see R13).
// Q stored BF16 (Qb). K/V in two half-head tables (KVlo: heads 0-3,
// KVhi: heads 4-7), 128 B rows.
// ---------------------------------------------------------------------------
__global__ __launch_bounds__(256) void qkv_kernel(
    const float* __restrict__ x, const ushort_t* __restrict__ Wt,
    const float* __restrict__ bq, const float* __restrict__ bk,
    const float* __restrict__ bv,
    ushort_t* __restrict__ Qb, ushort_t* __restrict__ KVlo,
    ushort_t* __restrict__ KVhi)
{
    int tid = threadIdx.x;
    int lane = tid & 63;
    int w = tid >> 6;
    int node = blockIdx.x * 64 + w * 16 + (lane & 15);
    int nclamp = node < N_NODES ? node : N_NODES - 1;
    int koff = (lane >> 4) * 8;

    U8 xf[2];
    #pragma unroll
    for (int kh = 0; kh < 2; ++kh) {
        const float* xb = &x[(size_t)nclamp * 64 + kh * 32 + koff];
        float4 a0 = *(const float4*)xb;
        float4 a1 = *(const float4*)(xb + 4);
        unsigned* xp = (unsigned*)&xf[kh];
        xp[0] = pkbf16(a0.x, a0.y); xp[1] = pkbf16(a0.z, a0.w);
        xp[2] = pkbf16(a1.x, a1.y); xp[3] = pkbf16(a1.z, a1.w);
    }

    f32x4 acc[3][4];
    #pragma unroll
    for (int m = 0; m < 3; ++m)
        #pragma unroll
        for (int ct = 0; ct < 4; ++ct)
            acc[m][ct] = (f32x4){0.f, 0.f, 0.f, 0.f};

    int colin = lane & 15;
    #pragma unroll
    for (int m = 0; m < 3; ++m) {
        const ushort_t* Wm = Wt + m * 4096;
        #pragma unroll
        for (int ct = 0; ct < 4; ++ct) {
            const ushort_t* wb = &Wm[(ct * 16 + colin) * 64 + koff];
            #pragma unroll
            for (int kh = 0; kh < 2; ++kh) {
                U8 wf;
                wf.u = *(const uint4*)(wb + kh * 32);
                acc[m][ct] = __builtin_amdgcn_mfma_f32_16x16x32_bf16(
                    wf.b, xf[kh].b, acc[m][ct], 0, 0, 0);
            }
        }
    }

    if (node < N_NODES) {
        int wc4 = (lane >> 4) * 4;
        #pragma unroll
        for (int ct = 0; ct < 4; ++ct) {
            int wc = ct * 16 + wc4;        // output col: head = wc>>3, dim = wc&7
            float4 qb = *(const float4*)&bq[wc];
            f32x4 a = acc[0][ct];
            *(uint2*)&Qb[(size_t)node * 64 + wc] =
                make_uint2(pkbf16(a[0] + qb.x, a[1] + qb.y),
                           pkbf16(a[2] + qb.z, a[3] + qb.w));
            int hh = wc >> 3;
            ushort_t* kvdst = (hh < 4 ? KVlo : KVhi)
                            + (size_t)node * 64 + (hh & 3) * 8 + (wc & 7);
            float4 kb = *(const float4*)&bk[wc];
            f32x4 k = acc[1][ct];
            *(uint2*)kvdst =
                make_uint2(pkbf16(k[0] + kb.x, k[1] + kb.y),
                           pkbf16(k[2] + kb.z, k[3] + kb.w));
            float4 vb = *(const float4*)&bv[wc];
            f32x4 v = acc[2][ct];
            *(uint2*)(kvdst + 32) =
                make_uint2(pkbf16(v[0] + vb.x, v[1] + vb.y),
                           pkbf16(v[2] + vb.z, v[3] + vb.w));
        }
    }
}

// ---------------------------------------------------------------------------
// Pass 1: bucket scatter, 1024 threads x 8192 edges per block (196 blocks).
// ---------------------------------------------------------------------------
__global__ __launch_bounds__(1024) void scatter_kernel(
    const int* __restrict__ ei, int* __restrict__ cursor,
    unsigned int* __restrict__ pairs)
{
    __shared__ int hist[NBUCKETS];
    __shared__ int bbs[NBUCKETS];
    int t = threadIdx.x;
    for (int i = t; i < NBUCKETS; i += 1024) hist[i] = 0;
    __syncthreads();

    const int4* r4 = (const int4*)ei;
    const int4* c4 = (const int4*)(ei + N_EDGES);
    int ia = blockIdx.x * 2048 + t;
    int ib = ia + 1024;
    bool va = (ia < N_EDGES / 4), vb = (ib < N_EDGES / 4);
    int4 rva = va ? r4[ia] : make_int4(0, 0, 0, 0);
    int4 cva = va ? c4[ia] : make_int4(0, 0, 0, 0);
    int4 rvb = vb ? r4[ib] : make_int4(0, 0, 0, 0);
    int4 cvb = vb ? c4[ib] : make_int4(0, 0, 0, 0);

    int rr[8], cc[8];
    rr[0] = rva.x; rr[1] = rva.y; rr[2] = rva.z; rr[3] = rva.w;
    rr[4] = rvb.x; rr[5] = rvb.y; rr[6] = rvb.z; rr[7] = rvb.w;
    cc[0] = cva.x; cc[1] = cva.y; cc[2] = cva.z; cc[3] = cva.w;
    cc[4] = cvb.x; cc[5] = cvb.y; cc[6] = cvb.z; cc[7] = cvb.w;

    int bkt[8], rnk[8];
    unsigned pk[8];
    #pragma unroll
    for (int j = 0; j < 8; ++j) {
        bool v = (j < 4) ? va : vb;
        int b = rr[j] >> BUCKET_SHIFT;
        bkt[j] = b;
        rnk[j] = v ? atomicAdd(&hist[b], 1) : 0;
        pk[j] = ((unsigned)(rr[j] & 255) << 17) | (unsigned)cc[j];
    }
    __syncthreads();
    for (int i = t; i < NBUCKETS; i += 1024) {
        int h = hist[i];
        if (h) bbs[i] = i * BCAP + atomicAdd(&cursor[i], h);
    }
    __syncthreads();
    #pragma unroll
    for (int j = 0; j < 8; ++j) {
        bool v = (j < 4) ? va : vb;
        if (v) pairs[bbs[bkt[j]] + rnk[j]] = pk[j];
    }
}

// ---------------------------------------------------------------------------
// Pass 2: one block per bucket, 512 threads (halves the serial block
// latency vs 256). Stage pairs in LDS; 4096-bin histogram keyed
// (node_local<<4 | col/6250) -> each node's edge list ordered by 16
// col-chunks of 0.8 MB/half (fits L2 even with wave desync; R18's 4x3.2MB
// was marginal). Scan over first 256 threads (wave-scan + wsum). Writes
// ordered col ids back IN PLACE. start[n] = b*BCAP + excl.
// ---------------------------------------------------------------------------
__global__ __launch_bounds__(512) void csr_build_kernel(
    unsigned int* __restrict__ pairs, const int* __restrict__ cursor,
    int* __restrict__ deg, int* __restrict__ start)
{
    __shared__ unsigned int lp[BCAP];        // 24 KB
    __shared__ int hist[4096];               // 16 KB
    __shared__ int wsum[4];
    int b = blockIdx.x, t = threadIdx.x;
    int cnt = cursor[b];
    unsigned int* bp = pairs + (size_t)b * BCAP;

    for (int i = t; i < cnt; i += 512) lp[i] = bp[i];
    for (int i = t; i < 4096; i += 512) hist[i] = 0;
    __syncthreads();
    for (int i = t; i < cnt; i += 512) {
        unsigned p = lp[i];
        unsigned col = p & 0x1FFFFu;
        int key = (int)((p >> 17) << 4) | (int)(col / CCHUNK);
        atomicAdd(&hist[key], 1);
    }
    __syncthreads();

    // threads 0..255: thread t owns node-bin t (16 chunk bins)
    if (t < 256) {
        int hv[16];
        int local = 0;
        #pragma unroll
        for (int c = 0; c < 16; ++c) { hv[c] = hist[16 * t + c]; local += hv[c]; }
        int lane = t & 63, w = t >> 6;
        int inc = local;
        #pragma unroll
        for (int off = 1; off < 64; off <<= 1) {
            int u = __shfl_up(inc, off);
            if (lane >= off) inc += u;
        }
        if (lane == 63) wsum[w] = inc;
        __syncthreads();
        int woff = 0;
        for (int i = 0; i < w; ++i) woff += wsum[i];
        int excl = woff + inc - local;
        int node = (b << BUCKET_SHIFT) + t;
        if (node < N_NODES) { deg[node] = local; start[node] = b * BCAP + excl; }
        int run = excl;
        #pragma unroll
        for (int c = 0; c < 16; ++c) { hist[16 * t + c] = run; run += hv[c]; }
    } else {
        __syncthreads();                     // match barrier in the t<256 path
    }
    __syncthreads();
    for (int i = t; i < cnt; i += 512) {
        unsigned p = lp[i];
        unsigned col = p & 0x1FFFFu;
        int key = (int)((p >> 17) << 4) | (int)(col / CCHUNK);
        int pos = atomicAdd(&hist[key], 1);
        bp[pos] = col;
    }
}

// ---------------------------------------------------------------------------
// K6: per-node softmax aggregation over HALF-HEAD tables (R17). Edge lists
// are col-chunk-ordered (csr) so the gather working set is ~0.8 MB at a
// time -> L2-resident. s/acc lane-local, zero cross-lane ops, ILP-2.
// ---------------------------------------------------------------------------
#define DOT8H(KW) (blo(KW.x) * q0 + bhi(KW.x) * q1                            \
                 + blo(KW.y) * q2 + bhi(KW.y) * q3                            \
                 + blo(KW.z) * q4 + bhi(KW.z) * q5                            \
                 + blo(KW.w) * q6 + bhi(KW.w) * q7)

#define ACC8H(P, VW)                                                          \
    acc[0] = fmaf(P, blo(VW.x), acc[0]);                                      \
    acc[1] = fmaf(P, bhi(VW.x), acc[1]);                                      \
    acc[2] = fmaf(P, blo(VW.y), acc[2]);                                      \
    acc[3] = fmaf(P, bhi(VW.y), acc[3]);                                      \
    acc[4] = fmaf(P, blo(VW.z), acc[4]);                                      \
    acc[5] = fmaf(P, bhi(VW.z), acc[5]);                                      \
    acc[6] = fmaf(P, blo(VW.w), acc[6]);                                      \
    acc[7] = fmaf(P, bhi(VW.w), acc[7]);

__global__ __launch_bounds__(256) void agg_kernel(
    const ushort_t* __restrict__ Qb, const ushort_t* __restrict__ KVlo,
    const ushort_t* __restrict__ KVhi,
    const int* __restrict__ start, const int* __restrict__ deg,
    const int* __restrict__ elist, ushort_t* __restrict__ aggb)
{
    int bid = blockIdx.x;
    int grp = bid & 7;
    int half = grp >> 2;                     // XCDs 0-3 -> lo, 4-7 -> hi
    int k = (bid >> 3) * 4 + (grp & 3);      // 64-node chunk id
    if (k >= NCHUNKS) return;

    int tid = threadIdx.x;
    int lane = tid & 63;
    int ns = lane >> 2;                      // node slot 0..15
    int h2 = lane & 3;                       // head within half
    int n = k * 64 + (tid >> 6) * 16 + ns;
    bool valid = n < N_NODES;
    int nc = valid ? n : N_NODES - 1;

    int d = deg[nc];
    int st = start[nc];
    const ushort_t* KV = half ? KVhi : KVlo;

    uint4 qw = *(const uint4*)&Qb[(size_t)nc * 64 + (half * 4 + h2) * 8];
    float q0 = blo(qw.x), q1 = bhi(qw.x), q2 = blo(qw.y), q3 = bhi(qw.y);
    float q4 = blo(qw.z), q5 = bhi(qw.z), q6 = blo(qw.w), q7 = bhi(qw.w);

    const float inv_scale = 0.35355339059327373f;  // 1/sqrt(8)
    float s = 0.f;
    float acc[8] = {0.f, 0.f, 0.f, 0.f, 0.f, 0.f, 0.f, 0.f};

    int j = 0;
    for (; j + 2 <= d; j += 2) {
        int c0 = elist[st + j];
        int c1 = elist[st + j + 1];
        const ushort_t* r0 = KV + (size_t)c0 * 64 + h2 * 8;
        const ushort_t* r1 = KV + (size_t)c1 * 64 + h2 * 8;
        uint4 kw0 = *(const uint4*)r0;
        uint4 kw1 = *(const uint4*)r1;
        uint4 vw0 = *(const uint4*)(r0 + 32);
        uint4 vw1 = *(const uint4*)(r1 + 32);
        float p0 = __expf(DOT8H(kw0) * inv_scale);
        float p1 = __expf(DOT8H(kw1) * inv_scale);
        s += p0 + p1;
        ACC8H(p0, vw0)
        ACC8H(p1, vw1)
    }
    if (j < d) {
        int c0 = elist[st + j];
        const ushort_t* r0 = KV + (size_t)c0 * 64 + h2 * 8;
        uint4 kw0 = *(const uint4*)r0;
        uint4 vw0 = *(const uint4*)(r0 + 32);
        float p0 = __expf(DOT8H(kw0) * inv_scale);
        s += p0;
        ACC8H(p0, vw0)
    }

    if (valid) {
        float inv = 1.f / (s + 1e-8f);
        *(uint4*)&aggb[(size_t)n * 64 + (half * 4 + h2) * 8] = make_uint4(
            pkbf16(acc[0] * inv, acc[1] * inv), pkbf16(acc[2] * inv, acc[3] * inv),
            pkbf16(acc[4] * inv, acc[5] * inv), pkbf16(acc[6] * inv, acc[7] * inv));
    }
}

// ---------------------------------------------------------------------------
// K7: output projection via MFMA. B-fragments load DIRECTLY from bf16 aggb.
// ---------------------------------------------------------------------------
__global__ __launch_bounds__(256) void out_kernel(
    const ushort_t* __restrict__ aggb, const ushort_t* __restrict__ Wto,
    const float* __restrict__ bo, float* __restrict__ out)
{
    int tid = threadIdx.x;
    int lane = tid & 63;
    int w = tid >> 6;
    int node = blockIdx.x * 64 + w * 16 + (lane & 15);
    int nclamp = node < N_NODES ? node : N_NODES - 1;
    int koff = (lane >> 4) * 8;

    U8 af[2];
    #pragma unroll
    for (int kh = 0; kh < 2; ++kh)
        af[kh].u = *(const uint4*)&aggb[(size_t)nclamp * 64 + kh * 32 + koff];

    f32x4 acc[4];
    #pragma unroll
    for (int ct = 0; ct < 4; ++ct) acc[ct] = (f32x4){0.f, 0.f, 0.f, 0.f};

    int colin = lane & 15;
    #pragma unroll
    for (int ct = 0; ct < 4; ++ct) {
        const ushort_t* wb = &Wto[(ct * 16 + colin) * 64 + koff];
        #pragma unroll
        for (int kh = 0; kh < 2; ++kh) {
            U8 wf;
            wf.u = *(const uint4*)(wb + kh * 32);
            acc[ct] = __builtin_amdgcn_mfma_f32_16x16x32_bf16(
                wf.b, af[kh].b, acc[ct], 0, 0, 0);
        }
    }

    if (node < N_NODES) {
        int wc4 = (lane >> 4) * 4;
        #pragma unroll
        for (int ct = 0; ct < 4; ++ct) {
            int wc = ct * 16 + wc4;
            float4 ob = *(const float4*)&bo[wc];
            f32x4 a = acc[ct];
            *(float4*)&out[(size_t)node * 64 + wc] =
                make_float4(a[0] + ob.x, a[1] + ob.y, a[2] + ob.z, a[3] + ob.w);
        }
    }
}

extern "C" void kernel_launch(void* const* d_in, const int* in_sizes, int n_in,
                              void* d_out, int out_size, void* d_ws, size_t ws_size,
                              hipStream_t stream)
{
    const float* x  = (const float*)d_in[0];
    const int*   ei = (const int*)  d_in[1];   // [2*E] flattened: row then col
    const float* Wq = (const float*)d_in[2];
    const float* bq = (const float*)d_in[3];
    const float* Wk = (const float*)d_in[4];
    const float* bk = (const float*)d_in[5];
    const float* Wv = (const float*)d_in[6];
    const float* bv = (const float*)d_in[7];
    const float* Wo = (const float*)d_in[8];
    const float* bo = (const float*)d_in[9];
    float* out = (float*)d_out;

    ushort_t* Qb   = (ushort_t*)d_ws;                      // N*64 bf16   12.8 MB
    ushort_t* KVlo = Qb + (size_t)N_NODES * 64;            // N*64 bf16   12.8 MB
    ushort_t* KVhi = KVlo + (size_t)N_NODES * 64;          // N*64 bf16   12.8 MB
    ushort_t* aggb = KVhi + (size_t)N_NODES * 64;          // N*64 bf16   12.8 MB
    int* deg    = (int*)(aggb + (size_t)N_NODES * 64);
    int* start  = deg + N_NODES;
    int* cursor = start + N_NODES;                         // 512 ints
    unsigned int* pairs = (unsigned int*)(cursor + 512);   // NBUCKETS*BCAP (elist aliases)
    ushort_t* Wt = (ushort_t*)(pairs + (size_t)NBUCKETS * BCAP);  // 4*64*64 bf16

    wtrans_kernel<<<1, 256, 0, stream>>>(Wq, Wk, Wv, Wo, Wt, cursor);
    qkv_kernel<<<NPROJ_BLOCKS, 256, 0, stream>>>(x, Wt, bq, bk, bv, Qb, KVlo, KVhi);
    scatter_kernel<<<SCAT_BLOCKS, 1024, 0, stream>>>(ei, cursor, pairs);
    csr_build_kernel<<<NBUCKETS, 512, 0, stream>>>(pairs, cursor, deg, start);
    agg_kernel<<<((NCHUNKS + 3) / 4) * 8, 256, 0, stream>>>(
        Qb, KVlo, KVhi, start, deg, (const int*)pairs, aggb);
    out_kernel<<<NPROJ_BLOCKS, 256, 0, stream>>>(aggb, Wt + 3 * 4096, bo, out);
}